// Round 9
// baseline (721.356 us; speedup 1.0000x reference)
//
#include <hip/hip_runtime.h>

#define NN 50000
#define EE 500000

typedef unsigned int u32;
typedef unsigned short ushort;
typedef __attribute__((ext_vector_type(8))) short short8v;
typedef __attribute__((ext_vector_type(4))) float float4v;

__device__ __forceinline__ ushort f2b(float f) {  // f32 -> bf16 RNE
  u32 u = __float_as_uint(f);
  u32 r = (u + 0x7fffu + ((u >> 16) & 1u)) >> 16;
  return (ushort)r;
}
__device__ __forceinline__ void gload16(const void* g, void* l) {
  __builtin_amdgcn_global_load_lds((const __attribute__((address_space(1))) void*)g,
                                   (__attribute__((address_space(3))) void*)l, 16, 0, 0);
}

// -------- prep: WT (3x bf16 n-major), V6T [64][256], xb (bf16), zero cnt3 --------
__global__ void prep_kernel(const float* __restrict__ W_gp, const float* __restrict__ W_pg,
                            const float* __restrict__ W_gg,
                            const float* __restrict__ as_gp, const float* __restrict__ as_pg,
                            const float* __restrict__ as_gg,
                            const float* __restrict__ ad_gp, const float* __restrict__ ad_pg,
                            const float* __restrict__ ad_gg,
                            const float* __restrict__ xg, const float* __restrict__ xp,
                            ushort* __restrict__ WT, ushort* __restrict__ V6T,
                            ushort* __restrict__ xb, int* __restrict__ cnt3) {
  int b = blockIdx.x;
  int k = threadIdx.x;
  if (b < 256) {  // weight transposes: WT[p][n][k] = W_p[k][n]
    int n = b;
    WT[(size_t)0 * 65536 + n * 256 + k] = f2b(W_gp[k * 256 + n]);
    WT[(size_t)1 * 65536 + n * 256 + k] = f2b(W_pg[k * 256 + n]);
    WT[(size_t)2 * 65536 + n * 256 + k] = f2b(W_gg[k * 256 + n]);
    return;
  }
  if (b == 256) {  // V6T: col g*8+h, row k.  v[k] = sum_c W[k][32h+c]*a[h][c]
#pragma unroll
    for (int g = 0; g < 6; ++g) {
      const float* W;
      const float* a;
      switch (g) {
        case 0: W = W_gp; a = as_gp; break;  // als gp (gene rows)
        case 1: W = W_gg; a = as_gg; break;  // als gg (gene rows)
        case 2: W = W_pg; a = ad_pg; break;  // ald pg (gene rows, dst)
        case 3: W = W_gg; a = ad_gg; break;  // ald gg (gene rows, dst)
        case 4: W = W_pg; a = as_pg; break;  // als pg (pheno rows)
        default: W = W_gp; a = ad_gp; break; // ald gp (pheno rows, dst)
      }
#pragma unroll
      for (int h = 0; h < 8; ++h) {
        float s = 0.f;
#pragma unroll
        for (int c = 0; c < 32; ++c) s += W[k * 256 + h * 32 + c] * a[h * 32 + c];
        V6T[(size_t)(g * 8 + h) * 256 + k] = f2b(s);
      }
    }
    for (int col = 48; col < 64; ++col) V6T[(size_t)col * 256 + k] = 0;  // pad
    return;
  }
  // xb convert + cnt3 zero
  int gid = (b - 257) * 256 + k;
  const int gstride = (gridDim.x - 257) * 256;
  for (int j = gid; j < 3 * NN; j += gstride) cnt3[j] = 0;
  const int tot = 2 * NN * 64;
  for (int i = gid; i < tot; i += gstride) {
    const float* src = (i < NN * 64) ? xg + (size_t)i * 4 : xp + ((size_t)i - (size_t)NN * 64) * 4;
    float4 v = *(const float4*)src;
    ushort4 o;
    o.x = f2b(v.x); o.y = f2b(v.y); o.z = f2b(v.z); o.w = f2b(v.w);
    *(ushort4*)&xb[(size_t)i * 4] = o;
  }
}

// ---------------- MFMA GEMM (h-producer): 128x128 tile, BK=32, gload_lds, dbuf ----------------
// blockIdx.y = p*2 + colhalf. Swapped-operand: lane holds h[row=..+rr][col=..+kb*4+i]
__global__ __launch_bounds__(256) void gemm_fused(
    const ushort* __restrict__ xb, const ushort* __restrict__ WT,
    ushort* __restrict__ hb3) {
  __shared__ ushort As[2][4096];  // [128 rows][32 k]
  __shared__ ushort Bs[2][4096];  // [128 cols][32 k]
  const int p = blockIdx.y >> 1;
  const int c0 = (blockIdx.y & 1) * 128;
  const ushort* x = xb + (p == 1 ? (size_t)NN * 256 : 0);
  const ushort* Wp = WT + (size_t)p * 65536 + (size_t)c0 * 256;
  ushort* hb = hb3 + (size_t)p * 12800000;
  const int r0 = blockIdx.x * 128;
  const int tid = threadIdx.x;
  const int l = tid & 63, w = tid >> 6;
  const int rr = l & 15, kb = l >> 4;
  const int wm = w >> 1, wn = w & 1;
  float4v acc[4][4];
#pragma unroll
  for (int mi = 0; mi < 4; ++mi)
#pragma unroll
    for (int ni = 0; ni < 4; ++ni) acc[mi][ni] = (float4v){0.f, 0.f, 0.f, 0.f};
  const int r1 = tid >> 2, g1 = tid & 3;
  const int r2 = 64 + (tid >> 2), g2 = tid & 3;

#define STAGE(buf, k0)                                                           \
  {                                                                              \
    gload16(&x[(size_t)(r0 + r1) * 256 + (k0) + g1 * 8], &As[buf][tid * 8]);     \
    gload16(&x[(size_t)(r0 + r2) * 256 + (k0) + g2 * 8], &As[buf][(tid + 256) * 8]); \
    gload16(&Wp[(size_t)r1 * 256 + (k0) + g1 * 8], &Bs[buf][tid * 8]);           \
    gload16(&Wp[(size_t)r2 * 256 + (k0) + g2 * 8], &Bs[buf][(tid + 256) * 8]);   \
  }

  STAGE(0, 0);
  __syncthreads();
#pragma unroll
  for (int k = 0; k < 8; ++k) {
    const int buf = k & 1;
    if (k < 7) STAGE(buf ^ 1, (k + 1) * 32);
    short8v af[4], bf[4];
#pragma unroll
    for (int t = 0; t < 4; ++t) {
      af[t] = *(const short8v*)&As[buf][(wm * 64 + t * 16 + rr) * 32 + kb * 8];
      bf[t] = *(const short8v*)&Bs[buf][(wn * 64 + t * 16 + rr) * 32 + kb * 8];
    }
#pragma unroll
    for (int mi = 0; mi < 4; ++mi)
#pragma unroll
      for (int ni = 0; ni < 4; ++ni)
        acc[mi][ni] = __builtin_amdgcn_mfma_f32_16x16x32_bf16(bf[ni], af[mi], acc[mi][ni], 0, 0, 0);
    __syncthreads();
  }
#undef STAGE
  // epilogue: direct bf16 store; lane holds h[row=r0+wm*64+mi*16+rr][col=c0+wn*64+ni*16+kb*4+i]
#pragma unroll
  for (int mi = 0; mi < 4; ++mi) {
    const int row = r0 + wm * 64 + mi * 16 + rr;
    if (row < NN) {
      ushort* hp = &hb[(size_t)row * 256 + c0 + wn * 64 + kb * 4];
#pragma unroll
      for (int ni = 0; ni < 4; ++ni) {
        uint2 o;
        o.x = (u32)f2b(acc[mi][ni][0]) | ((u32)f2b(acc[mi][ni][1]) << 16);
        o.y = (u32)f2b(acc[mi][ni][2]) | ((u32)f2b(acc[mi][ni][3]) << 16);
        *(uint2*)&hp[ni * 16] = o;
      }
    }
  }
}

// -------- al_mfma: al6 = xball(2N x 256) @ V6T(64 cols); scatter to per-phase arrays --------
__global__ __launch_bounds__(256) void al_mfma(const ushort* __restrict__ xb,
                                               const ushort* __restrict__ V6T,
                                               float* __restrict__ als3,
                                               float* __restrict__ ald3) {
  __shared__ ushort BsV[16384];   // 64 cols x 256 k
  __shared__ ushort As[2][2048];  // 64 rows x 32 k, dbuf
  const int tid = threadIdx.x;
  const int r0 = blockIdx.x * 64;
  const int l = tid & 63, w = tid >> 6;
  const int rr = l & 15, kb = l >> 4;
#pragma unroll
  for (int q = 0; q < 8; ++q) {  // 2048 granules: full V6T
    int s = tid + q * 256;
    gload16(&V6T[(size_t)(s >> 5) * 256 + (s & 31) * 8], &BsV[s * 8]);
  }
  gload16(&xb[(size_t)(r0 + (tid >> 2)) * 256 + (tid & 3) * 8], &As[0][tid * 8]);
  __syncthreads();
  float4v acc[4];
#pragma unroll
  for (int mi = 0; mi < 4; ++mi) acc[mi] = (float4v){0.f, 0.f, 0.f, 0.f};
#pragma unroll
  for (int k = 0; k < 8; ++k) {
    const int buf = k & 1;
    if (k < 7)
      gload16(&xb[(size_t)(r0 + (tid >> 2)) * 256 + (k + 1) * 32 + (tid & 3) * 8],
              &As[buf ^ 1][tid * 8]);
    short8v bfv = *(const short8v*)&BsV[(w * 16 + rr) * 256 + k * 32 + kb * 8];
#pragma unroll
    for (int mi = 0; mi < 4; ++mi) {
      short8v afv = *(const short8v*)&As[buf][(mi * 16 + rr) * 32 + kb * 8];
      acc[mi] = __builtin_amdgcn_mfma_f32_16x16x32_bf16(bfv, afv, acc[mi], 0, 0, 0);
    }
    __syncthreads();
  }
  // lane holds D[row=r0+mi*16+rr][col=w*16+kb*4+i]; group g = w*2+(kb>>1); idx=(kb&1)*4
  const int g = w * 2 + (kb >> 1);
  const int idx = (kb & 1) * 4;
#pragma unroll
  for (int mi = 0; mi < 4; ++mi) {
    int grow = r0 + mi * 16 + rr;
    float4 val = make_float4(acc[mi][0], acc[mi][1], acc[mi][2], acc[mi][3]);
    if (grow < NN) {
      float* arr = g == 0 ? als3 : g == 1 ? als3 + 800000 : g == 2 ? ald3 + 400000
                 : g == 3 ? ald3 + 800000 : nullptr;
      if (arr) *(float4*)&arr[(size_t)grow * 8 + idx] = val;
    } else if (grow < 2 * NN) {
      int r = grow - NN;
      float* arr = g == 4 ? als3 + 400000 : g == 5 ? ald3 : nullptr;
      if (arr) *(float4*)&arr[(size_t)r * 8 + idx] = val;
    }
  }
}

// -------- CSR build --------
__global__ void hist3_kernel(const int* __restrict__ e0, const int* __restrict__ e1,
                             const int* __restrict__ e2, int* __restrict__ cnt3) {
  int i = blockIdx.x * blockDim.x + threadIdx.x;
  if (i >= 3 * EE) return;
  int which = i >= 2 * EE ? 2 : (i >= EE ? 1 : 0);
  const int* ei = which == 0 ? e0 : (which == 1 ? e1 : e2);
  int e = i - which * EE;
  atomicAdd(&cnt3[which * NN + ei[EE + e]], 1);
}

__global__ __launch_bounds__(1024) void scan1_kernel(int* __restrict__ cnt,
                                                     int* __restrict__ bsum, int n) {
  __shared__ int ws[16];
  int i = blockIdx.x * 1024 + threadIdx.x;
  const int lane = threadIdx.x & 63, w = threadIdx.x >> 6;
  int v = (i < n) ? cnt[i] : 0;
  int s = v;
#pragma unroll
  for (int off = 1; off < 64; off <<= 1) {
    int t = __shfl_up(s, off);
    if (lane >= off) s += t;
  }
  if (lane == 63) ws[w] = s;
  __syncthreads();
  if (threadIdx.x == 0) {
    int r = 0;
#pragma unroll
    for (int k = 0; k < 16; ++k) { int t = ws[k]; ws[k] = r; r += t; }
    bsum[blockIdx.x] = r;
  }
  __syncthreads();
  if (i < n) cnt[i] = s - v + ws[w];
}

__global__ void scan2_kernel(int* __restrict__ bsum, int nb) {
  __shared__ int ws[4];
  int t = threadIdx.x;  // 256
  const int lane = t & 63, w = t >> 6;
  int v = (t < nb) ? bsum[t] : 0;
  int s = v;
#pragma unroll
  for (int off = 1; off < 64; off <<= 1) {
    int tt = __shfl_up(s, off);
    if (lane >= off) s += tt;
  }
  if (lane == 63) ws[w] = s;
  __syncthreads();
  if (t == 0) {
    int r = 0;
#pragma unroll
    for (int k = 0; k < 4; ++k) { int tt = ws[k]; ws[k] = r; r += tt; }
  }
  __syncthreads();
  if (t < nb) bsum[t] = s - v + ws[w];
}

__global__ __launch_bounds__(1024) void scan3_kernel(const int* __restrict__ part,
                                                     const int* __restrict__ bsum,
                                                     int* __restrict__ row_start,
                                                     int* __restrict__ cursor, int n, int total) {
  int i = blockIdx.x * 1024 + threadIdx.x;
  if (i == 0) row_start[n] = total;
  if (i >= n) return;
  int v = part[i] + bsum[blockIdx.x];
  row_start[i] = v;
  cursor[i] = v;
}

__global__ void permute3_kernel(const int* __restrict__ e0, const int* __restrict__ e1,
                                const int* __restrict__ e2, int* __restrict__ cur3,
                                int* __restrict__ srcs3) {
  int i = blockIdx.x * blockDim.x + threadIdx.x;
  if (i >= 3 * EE) return;
  int which = i >= 2 * EE ? 2 : (i >= EE ? 1 : 0);
  const int* ei = which == 0 ? e0 : (which == 1 ? e1 : e2);
  int e = i - which * EE;
  int d = ei[EE + e];
  int pos = atomicAdd(&cur3[which * NN + d], 1);
  srcs3[pos] = ei[e];
}

// -------- gather+LN: one wave per output row; gene waves do pg+gg ranges; fused LN --------
__global__ __launch_bounds__(256) void gat_gather_ln(
    const int* __restrict__ row3, const int* __restrict__ srcs3,
    const ushort* __restrict__ hb3, const float* __restrict__ als3,
    const float* __restrict__ ald3,
    const float* __restrict__ xg, const float* __restrict__ xp,
    const float* __restrict__ b_gp, const float* __restrict__ b_pg,
    const float* __restrict__ b_gg,
    const float* __restrict__ lng_g, const float* __restrict__ lnb_g,
    const float* __restrict__ lng_p, const float* __restrict__ lnb_p,
    float* __restrict__ out) {
  __shared__ float exs[4][8][68];
  __shared__ int ssrc[4][64];
  const int l = threadIdx.x & 63;
  const int wv = threadIdx.x >> 6;
  const int slot = blockIdx.x * 4 + wv;
  if (slot >= 2 * NN) return;
  const bool gene = (slot < NN);
  const int d = gene ? slot : slot - NN;
  const int sl = l & 31;
  const int half = l >> 5;
  const int hh = sl >> 2;
  float vout[8] = {0.f, 0.f, 0.f, 0.f, 0.f, 0.f, 0.f, 0.f};
  const int nph = gene ? 2 : 1;
  for (int q = 0; q < nph; ++q) {
    const int phase = gene ? (1 + q) : 0;
    const int cslot = phase * NN + d;
    const ushort* hmat = hb3 + (size_t)phase * 12800000;
    const float* al_s = als3 + (size_t)phase * 400000;
    const float* al_d = ald3 + (size_t)phase * 400000;
    const int rs = row3[cslot], re = row3[cslot + 1];
    if (re == rs) continue;
    float4 ad0 = *(const float4*)&al_d[(size_t)d * 8];
    float4 ad1 = *(const float4*)&al_d[(size_t)d * 8 + 4];
    const float ald[8] = {ad0.x, ad0.y, ad0.z, ad0.w, ad1.x, ad1.y, ad1.z, ad1.w};
    float den = 0.f;
    float acc8[8] = {0.f, 0.f, 0.f, 0.f, 0.f, 0.f, 0.f, 0.f};
    const ushort* hrow = hmat + sl * 8;
    for (int base = rs; base < re; base += 64) {
      int e = base + l;
      int chunk = min(64, re - base);
      float ex[8] = {0.f, 0.f, 0.f, 0.f, 0.f, 0.f, 0.f, 0.f};
      int s = 0;
      if (e < re) {
        s = srcs3[e];
        float4 s0 = *(const float4*)&al_s[(size_t)s * 8];
        float4 s1 = *(const float4*)&al_s[(size_t)s * 8 + 4];
        float a[8] = {s0.x + ald[0], s0.y + ald[1], s0.z + ald[2], s0.w + ald[3],
                      s1.x + ald[4], s1.y + ald[5], s1.z + ald[6], s1.w + ald[7]};
#pragma unroll
        for (int h = 0; h < 8; ++h) ex[h] = __expf(fmaxf(a[h], 0.2f * a[h]));
      }
      ssrc[wv][l] = s;
#pragma unroll
      for (int h = 0; h < 8; ++h) exs[wv][h][l] = ex[h];
      // wave-synchronous LDS (per-wave region); 2 edges per half per j-iter
      int chunkr = (chunk + 3) & ~3;
      for (int j = 0; j < chunkr; j += 4) {
        int ja = j + half, jb = j + 2 + half;
        int sa = ssrc[wv][ja], sb = ssrc[wv][jb];
        float wa = exs[wv][hh][ja], wb = exs[wv][hh][jb];
        uint4 pa = *(const uint4*)&hrow[(size_t)sa * 256];
        uint4 pb = *(const uint4*)&hrow[(size_t)sb * 256];
        den += wa + wb;
        acc8[0] += __uint_as_float(pa.x << 16) * wa + __uint_as_float(pb.x << 16) * wb;
        acc8[1] += __uint_as_float(pa.x & 0xffff0000u) * wa + __uint_as_float(pb.x & 0xffff0000u) * wb;
        acc8[2] += __uint_as_float(pa.y << 16) * wa + __uint_as_float(pb.y << 16) * wb;
        acc8[3] += __uint_as_float(pa.y & 0xffff0000u) * wa + __uint_as_float(pb.y & 0xffff0000u) * wb;
        acc8[4] += __uint_as_float(pa.z << 16) * wa + __uint_as_float(pb.z << 16) * wb;
        acc8[5] += __uint_as_float(pa.z & 0xffff0000u) * wa + __uint_as_float(pb.z & 0xffff0000u) * wb;
        acc8[6] += __uint_as_float(pa.w << 16) * wa + __uint_as_float(pb.w << 16) * wb;
        acc8[7] += __uint_as_float(pa.w & 0xffff0000u) * wa + __uint_as_float(pb.w & 0xffff0000u) * wb;
      }
    }
#pragma unroll
    for (int i = 0; i < 8; ++i) acc8[i] += __shfl_xor(acc8[i], 32);
    den += __shfl_xor(den, 32);
    float wd = 1.f / (den + 1e-16f);
#pragma unroll
    for (int i = 0; i < 8; ++i) vout[i] += acc8[i] * wd;
  }
  // residual + biases
  const float* x = gene ? xg : xp;
  float4 xa = *(const float4*)&x[(size_t)d * 256 + sl * 8];
  float4 xbv = *(const float4*)&x[(size_t)d * 256 + sl * 8 + 4];
  float4 ba, bb;
  if (gene) {
    float4 p1 = *(const float4*)&b_pg[sl * 8];
    float4 p2 = *(const float4*)&b_pg[sl * 8 + 4];
    float4 q1 = *(const float4*)&b_gg[sl * 8];
    float4 q2 = *(const float4*)&b_gg[sl * 8 + 4];
    ba = make_float4(p1.x + q1.x, p1.y + q1.y, p1.z + q1.z, p1.w + q1.w);
    bb = make_float4(p2.x + q2.x, p2.y + q2.y, p2.z + q2.z, p2.w + q2.w);
  } else {
    ba = *(const float4*)&b_gp[sl * 8];
    bb = *(const float4*)&b_gp[sl * 8 + 4];
  }
  vout[0] += xa.x + ba.x; vout[1] += xa.y + ba.y; vout[2] += xa.z + ba.z; vout[3] += xa.w + ba.w;
  vout[4] += xbv.x + bb.x; vout[5] += xbv.y + bb.y; vout[6] += xbv.z + bb.z; vout[7] += xbv.w + bb.w;
  // LayerNorm over 256 ch (32 lanes x 8 ch per half; halves hold duplicates)
  float s = 0.f, ss = 0.f;
#pragma unroll
  for (int i = 0; i < 8; ++i) { s += vout[i]; ss += vout[i] * vout[i]; }
#pragma unroll
  for (int off = 1; off < 32; off <<= 1) {
    s += __shfl_xor(s, off);
    ss += __shfl_xor(ss, off);
  }
  float mu = s * (1.f / 256.f);
  float var = ss * (1.f / 256.f) - mu * mu;
  float rstd = rsqrtf(var + 1e-5f);
  const float* lg = gene ? lng_g : lng_p;
  const float* lb = gene ? lnb_g : lnb_p;
  float4 g1 = *(const float4*)&lg[sl * 8];
  float4 g2 = *(const float4*)&lg[sl * 8 + 4];
  float4 c1 = *(const float4*)&lb[sl * 8];
  float4 c2 = *(const float4*)&lb[sl * 8 + 4];
  if (half == 0) {
    float* op = &out[(size_t)slot * 256 + sl * 8];
    float4 o1 = make_float4((vout[0] - mu) * rstd * g1.x + c1.x,
                            (vout[1] - mu) * rstd * g1.y + c1.y,
                            (vout[2] - mu) * rstd * g1.z + c1.z,
                            (vout[3] - mu) * rstd * g1.w + c1.w);
    float4 o2 = make_float4((vout[4] - mu) * rstd * g2.x + c2.x,
                            (vout[5] - mu) * rstd * g2.y + c2.y,
                            (vout[6] - mu) * rstd * g2.z + c2.z,
                            (vout[7] - mu) * rstd * g2.w + c2.w);
    *(float4*)op = o1;
    *(float4*)(op + 4) = o2;
  }
}

extern "C" void kernel_launch(void* const* d_in, const int* in_sizes, int n_in,
                              void* d_out, int out_size, void* d_ws, size_t ws_size,
                              hipStream_t stream) {
  const float* x_gene = (const float*)d_in[0];
  const float* x_pheno = (const float*)d_in[1];
  const int* ei_gp = (const int*)d_in[2];
  const int* ei_pg = (const int*)d_in[3];
  const int* ei_gg = (const int*)d_in[4];
  const float* W_gp = (const float*)d_in[5];
  const float* a_s_gp = (const float*)d_in[6];
  const float* a_d_gp = (const float*)d_in[7];
  const float* b_gp = (const float*)d_in[8];
  const float* W_pg = (const float*)d_in[9];
  const float* a_s_pg = (const float*)d_in[10];
  const float* a_d_pg = (const float*)d_in[11];
  const float* b_pg = (const float*)d_in[12];
  const float* W_gg = (const float*)d_in[13];
  const float* a_s_gg = (const float*)d_in[14];
  const float* a_d_gg = (const float*)d_in[15];
  const float* b_gg = (const float*)d_in[16];
  const float* ln_g_gene = (const float*)d_in[17];
  const float* ln_b_gene = (const float*)d_in[18];
  const float* ln_g_ph = (const float*)d_in[19];
  const float* ln_b_ph = (const float*)d_in[20];
  float* out = (float*)d_out;

  float* ws = (float*)d_ws;
  ushort* hb3 = (ushort*)ws;                    // 3 x 12.8M bf16 = 19.2M f32
  ushort* xb = (ushort*)(ws + 19200000);        // >=100156 rows x 256 bf16
  float* als3 = ws + 32020000;                  // 3 x 400k f32
  float* ald3 = ws + 33220000;                  // 3 x 400k f32
  ushort* WT = (ushort*)(ws + 34420000);        // 3 x 65536 bf16
  ushort* V6T = (ushort*)(ws + 34520000);       // 64 x 256 bf16
  int* ibase = (int*)(ws + 34530000);
  int* cnt3 = ibase;                            // 150016
  int* row3 = ibase + 150016;                   // 150016
  int* cur3 = ibase + 300032;                   // 150016
  int* bsum = ibase + 450048;                   // 256
  int* srcs3 = ibase + 450304;                  // 1500000

  const int NT = 3 * NN;
  const int nb = (NT + 1023) / 1024;  // 147
  const int e3blk = (3 * EE + 255) / 256;

  // ---------- prep: WT, V6T, xb, zero cnt3 ----------
  prep_kernel<<<257 + 2048, 256, 0, stream>>>(W_gp, W_pg, W_gg, a_s_gp, a_s_pg, a_s_gg,
                                              a_d_gp, a_d_pg, a_d_gg, x_gene, x_pheno,
                                              WT, V6T, xb, cnt3);

  // ---------- joint CSR build ----------
  hist3_kernel<<<e3blk, 256, 0, stream>>>(ei_gp, ei_pg, ei_gg, cnt3);
  scan1_kernel<<<nb, 1024, 0, stream>>>(cnt3, bsum, NT);
  scan2_kernel<<<1, 256, 0, stream>>>(bsum, nb);
  scan3_kernel<<<nb, 1024, 0, stream>>>(cnt3, bsum, row3, cur3, NT, 3 * EE);
  permute3_kernel<<<e3blk, 256, 0, stream>>>(ei_gp, ei_pg, ei_gg, cur3, srcs3);

  // ---------- h GEMMs (pure producer) ----------
  gemm_fused<<<dim3(391, 6), 256, 0, stream>>>(xb, WT, hb3);

  // ---------- attention logits (all 6 projections) ----------
  al_mfma<<<(2 * NN + 63) / 64, 256, 0, stream>>>(xb, V6T, als3, ald3);

  // ---------- gather + residual + bias + LayerNorm (writes final output) ----------
  gat_gather_ln<<<(2 * NN + 3) / 4, 256, 0, stream>>>(
      row3, srcs3, hb3, als3, ald3, x_gene, x_pheno, b_gp, b_pg, b_gg,
      ln_g_gene, ln_b_gene, ln_g_ph, ln_b_ph, out);
}

// Round 10
// 424.532 us; speedup vs baseline: 1.6992x; 1.6992x over previous
//
#include <hip/hip_runtime.h>

#define NN 50000
#define EE 500000

typedef unsigned int u32;
typedef unsigned short ushort;
typedef __attribute__((ext_vector_type(8))) short short8v;
typedef __attribute__((ext_vector_type(4))) float float4v;

__device__ __forceinline__ ushort f2b(float f) {  // f32 -> bf16 RNE
  u32 u = __float_as_uint(f);
  u32 r = (u + 0x7fffu + ((u >> 16) & 1u)) >> 16;
  return (ushort)r;
}
__device__ __forceinline__ void gload16(const void* g, void* l) {
  __builtin_amdgcn_global_load_lds((const __attribute__((address_space(1))) void*)g,
                                   (__attribute__((address_space(3))) void*)l, 16, 0, 0);
}

// -------- prep: WT (3x bf16 n-major), V6T [64][256], xb (bf16), zero cnt3 --------
// b<256: W transpose. b in [256,304): V6T fold, one block per (g,h). b==304: V6T pad.
// b>=305: xb convert + cnt3 zero.
__global__ void prep_kernel(const float* __restrict__ W_gp, const float* __restrict__ W_pg,
                            const float* __restrict__ W_gg,
                            const float* __restrict__ as_gp, const float* __restrict__ as_pg,
                            const float* __restrict__ as_gg,
                            const float* __restrict__ ad_gp, const float* __restrict__ ad_pg,
                            const float* __restrict__ ad_gg,
                            const float* __restrict__ xg, const float* __restrict__ xp,
                            ushort* __restrict__ WT, ushort* __restrict__ V6T,
                            ushort* __restrict__ xb, int* __restrict__ cnt3) {
  int b = blockIdx.x;
  int k = threadIdx.x;
  if (b < 256) {  // weight transposes: WT[p][n][k] = W_p[k][n]
    int n = b;
    WT[(size_t)0 * 65536 + n * 256 + k] = f2b(W_gp[k * 256 + n]);
    WT[(size_t)1 * 65536 + n * 256 + k] = f2b(W_pg[k * 256 + n]);
    WT[(size_t)2 * 65536 + n * 256 + k] = f2b(W_gg[k * 256 + n]);
    return;
  }
  if (b < 304) {  // V6T fold: col g*8+h, row k.  v[k] = sum_c W[k][32h+c]*a[h][c]
    int idx = b - 256;
    int g = idx >> 3, h = idx & 7;
    const float* W;
    const float* a;
    switch (g) {
      case 0: W = W_gp; a = as_gp; break;  // als gp (gene rows)
      case 1: W = W_gg; a = as_gg; break;  // als gg (gene rows)
      case 2: W = W_pg; a = ad_pg; break;  // ald pg (gene rows, dst)
      case 3: W = W_gg; a = ad_gg; break;  // ald gg (gene rows, dst)
      case 4: W = W_pg; a = as_pg; break;  // als pg (pheno rows)
      default: W = W_gp; a = ad_gp; break; // ald gp (pheno rows, dst)
    }
    const float4* wrow = (const float4*)&W[(size_t)k * 256 + h * 32];
    const float4* arow = (const float4*)&a[h * 32];
    float s = 0.f;
#pragma unroll
    for (int q = 0; q < 8; ++q) {
      float4 wv = wrow[q];
      float4 av = arow[q];
      s += wv.x * av.x + wv.y * av.y + wv.z * av.z + wv.w * av.w;
    }
    V6T[(size_t)(g * 8 + h) * 256 + k] = f2b(s);
    return;
  }
  if (b == 304) {  // pad cols 48..63
#pragma unroll
    for (int col = 48; col < 64; ++col) V6T[(size_t)col * 256 + k] = 0;
    return;
  }
  // xb convert + cnt3 zero
  int gid = (b - 305) * 256 + k;
  const int gstride = (gridDim.x - 305) * 256;
  for (int j = gid; j < 3 * NN; j += gstride) cnt3[j] = 0;
  const int tot = 2 * NN * 64;
  for (int i = gid; i < tot; i += gstride) {
    const float* src = (i < NN * 64) ? xg + (size_t)i * 4 : xp + ((size_t)i - (size_t)NN * 64) * 4;
    float4 v = *(const float4*)src;
    ushort4 o;
    o.x = f2b(v.x); o.y = f2b(v.y); o.z = f2b(v.z); o.w = f2b(v.w);
    *(ushort4*)&xb[(size_t)i * 4] = o;
  }
}

// ---------------- MFMA GEMM (h-producer): 128x128 tile, BK=32, gload_lds, dbuf ----------------
// blockIdx.y = p*2 + colhalf. Swapped-operand: lane holds h[row=..+rr][col=..+kb*4+i]
__global__ __launch_bounds__(256) void gemm_fused(
    const ushort* __restrict__ xb, const ushort* __restrict__ WT,
    ushort* __restrict__ hb3) {
  __shared__ ushort As[2][4096];  // [128 rows][32 k]
  __shared__ ushort Bs[2][4096];  // [128 cols][32 k]
  const int p = blockIdx.y >> 1;
  const int c0 = (blockIdx.y & 1) * 128;
  const ushort* x = xb + (p == 1 ? (size_t)NN * 256 : 0);
  const ushort* Wp = WT + (size_t)p * 65536 + (size_t)c0 * 256;
  ushort* hb = hb3 + (size_t)p * 12800000;
  const int r0 = blockIdx.x * 128;
  const int tid = threadIdx.x;
  const int l = tid & 63, w = tid >> 6;
  const int rr = l & 15, kb = l >> 4;
  const int wm = w >> 1, wn = w & 1;
  float4v acc[4][4];
#pragma unroll
  for (int mi = 0; mi < 4; ++mi)
#pragma unroll
    for (int ni = 0; ni < 4; ++ni) acc[mi][ni] = (float4v){0.f, 0.f, 0.f, 0.f};
  const int r1 = tid >> 2, g1 = tid & 3;
  const int r2 = 64 + (tid >> 2), g2 = tid & 3;

#define STAGE(buf, k0)                                                           \
  {                                                                              \
    gload16(&x[(size_t)(r0 + r1) * 256 + (k0) + g1 * 8], &As[buf][tid * 8]);     \
    gload16(&x[(size_t)(r0 + r2) * 256 + (k0) + g2 * 8], &As[buf][(tid + 256) * 8]); \
    gload16(&Wp[(size_t)r1 * 256 + (k0) + g1 * 8], &Bs[buf][tid * 8]);           \
    gload16(&Wp[(size_t)r2 * 256 + (k0) + g2 * 8], &Bs[buf][(tid + 256) * 8]);   \
  }

  STAGE(0, 0);
  __syncthreads();
#pragma unroll
  for (int k = 0; k < 8; ++k) {
    const int buf = k & 1;
    if (k < 7) STAGE(buf ^ 1, (k + 1) * 32);
    short8v af[4], bf[4];
#pragma unroll
    for (int t = 0; t < 4; ++t) {
      af[t] = *(const short8v*)&As[buf][(wm * 64 + t * 16 + rr) * 32 + kb * 8];
      bf[t] = *(const short8v*)&Bs[buf][(wn * 64 + t * 16 + rr) * 32 + kb * 8];
    }
#pragma unroll
    for (int mi = 0; mi < 4; ++mi)
#pragma unroll
      for (int ni = 0; ni < 4; ++ni)
        acc[mi][ni] = __builtin_amdgcn_mfma_f32_16x16x32_bf16(bf[ni], af[mi], acc[mi][ni], 0, 0, 0);
    __syncthreads();
  }
#undef STAGE
  // epilogue: direct bf16 store; lane holds h[row=r0+wm*64+mi*16+rr][col=c0+wn*64+ni*16+kb*4+i]
#pragma unroll
  for (int mi = 0; mi < 4; ++mi) {
    const int row = r0 + wm * 64 + mi * 16 + rr;
    if (row < NN) {
      ushort* hp = &hb[(size_t)row * 256 + c0 + wn * 64 + kb * 4];
#pragma unroll
      for (int ni = 0; ni < 4; ++ni) {
        uint2 o;
        o.x = (u32)f2b(acc[mi][ni][0]) | ((u32)f2b(acc[mi][ni][1]) << 16);
        o.y = (u32)f2b(acc[mi][ni][2]) | ((u32)f2b(acc[mi][ni][3]) << 16);
        *(uint2*)&hp[ni * 16] = o;
      }
    }
  }
}

// -------- al_mfma: al6 = xball(2N x 256) @ V6T(64 cols); scatter to per-phase arrays --------
__global__ __launch_bounds__(256) void al_mfma(const ushort* __restrict__ xb,
                                               const ushort* __restrict__ V6T,
                                               float* __restrict__ als3,
                                               float* __restrict__ ald3) {
  __shared__ ushort BsV[16384];   // 64 cols x 256 k
  __shared__ ushort As[2][2048];  // 64 rows x 32 k, dbuf
  const int tid = threadIdx.x;
  const int r0 = blockIdx.x * 64;
  const int l = tid & 63, w = tid >> 6;
  const int rr = l & 15, kb = l >> 4;
#pragma unroll
  for (int q = 0; q < 8; ++q) {  // 2048 granules: full V6T
    int s = tid + q * 256;
    gload16(&V6T[(size_t)(s >> 5) * 256 + (s & 31) * 8], &BsV[s * 8]);
  }
  gload16(&xb[(size_t)(r0 + (tid >> 2)) * 256 + (tid & 3) * 8], &As[0][tid * 8]);
  __syncthreads();
  float4v acc[4];
#pragma unroll
  for (int mi = 0; mi < 4; ++mi) acc[mi] = (float4v){0.f, 0.f, 0.f, 0.f};
#pragma unroll
  for (int k = 0; k < 8; ++k) {
    const int buf = k & 1;
    if (k < 7)
      gload16(&xb[(size_t)(r0 + (tid >> 2)) * 256 + (k + 1) * 32 + (tid & 3) * 8],
              &As[buf ^ 1][tid * 8]);
    short8v bfv = *(const short8v*)&BsV[(w * 16 + rr) * 256 + k * 32 + kb * 8];
#pragma unroll
    for (int mi = 0; mi < 4; ++mi) {
      short8v afv = *(const short8v*)&As[buf][(mi * 16 + rr) * 32 + kb * 8];
      acc[mi] = __builtin_amdgcn_mfma_f32_16x16x32_bf16(bfv, afv, acc[mi], 0, 0, 0);
    }
    __syncthreads();
  }
  // lane holds D[row=r0+mi*16+rr][col=w*16+kb*4+i]; group g = w*2+(kb>>1); idx=(kb&1)*4
  const int g = w * 2 + (kb >> 1);
  const int idx = (kb & 1) * 4;
#pragma unroll
  for (int mi = 0; mi < 4; ++mi) {
    int grow = r0 + mi * 16 + rr;
    float4 val = make_float4(acc[mi][0], acc[mi][1], acc[mi][2], acc[mi][3]);
    if (grow < NN) {
      float* arr = g == 0 ? als3 : g == 1 ? als3 + 800000 : g == 2 ? ald3 + 400000
                 : g == 3 ? ald3 + 800000 : nullptr;
      if (arr) *(float4*)&arr[(size_t)grow * 8 + idx] = val;
    } else if (grow < 2 * NN) {
      int r = grow - NN;
      float* arr = g == 4 ? als3 + 400000 : g == 5 ? ald3 : nullptr;
      if (arr) *(float4*)&arr[(size_t)r * 8 + idx] = val;
    }
  }
}

// -------- CSR build --------
__global__ void hist3_kernel(const int* __restrict__ e0, const int* __restrict__ e1,
                             const int* __restrict__ e2, int* __restrict__ cnt3) {
  int i = blockIdx.x * blockDim.x + threadIdx.x;
  if (i >= 3 * EE) return;
  int which = i >= 2 * EE ? 2 : (i >= EE ? 1 : 0);
  const int* ei = which == 0 ? e0 : (which == 1 ? e1 : e2);
  int e = i - which * EE;
  atomicAdd(&cnt3[which * NN + ei[EE + e]], 1);
}

__global__ __launch_bounds__(1024) void scan1_kernel(int* __restrict__ cnt,
                                                     int* __restrict__ bsum, int n) {
  __shared__ int ws[16];
  int i = blockIdx.x * 1024 + threadIdx.x;
  const int lane = threadIdx.x & 63, w = threadIdx.x >> 6;
  int v = (i < n) ? cnt[i] : 0;
  int s = v;
#pragma unroll
  for (int off = 1; off < 64; off <<= 1) {
    int t = __shfl_up(s, off);
    if (lane >= off) s += t;
  }
  if (lane == 63) ws[w] = s;
  __syncthreads();
  if (threadIdx.x == 0) {
    int r = 0;
#pragma unroll
    for (int k = 0; k < 16; ++k) { int t = ws[k]; ws[k] = r; r += t; }
    bsum[blockIdx.x] = r;
  }
  __syncthreads();
  if (i < n) cnt[i] = s - v + ws[w];
}

__global__ void scan2_kernel(int* __restrict__ bsum, int nb) {
  __shared__ int ws[4];
  int t = threadIdx.x;  // 256
  const int lane = t & 63, w = t >> 6;
  int v = (t < nb) ? bsum[t] : 0;
  int s = v;
#pragma unroll
  for (int off = 1; off < 64; off <<= 1) {
    int tt = __shfl_up(s, off);
    if (lane >= off) s += tt;
  }
  if (lane == 63) ws[w] = s;
  __syncthreads();
  if (t == 0) {
    int r = 0;
#pragma unroll
    for (int k = 0; k < 4; ++k) { int tt = ws[k]; ws[k] = r; r += tt; }
  }
  __syncthreads();
  if (t < nb) bsum[t] = s - v + ws[w];
}

__global__ __launch_bounds__(1024) void scan3_kernel(const int* __restrict__ part,
                                                     const int* __restrict__ bsum,
                                                     int* __restrict__ row_start,
                                                     int* __restrict__ cursor, int n, int total) {
  int i = blockIdx.x * 1024 + threadIdx.x;
  if (i == 0) row_start[n] = total;
  if (i >= n) return;
  int v = part[i] + bsum[blockIdx.x];
  row_start[i] = v;
  cursor[i] = v;
}

__global__ void permute3_kernel(const int* __restrict__ e0, const int* __restrict__ e1,
                                const int* __restrict__ e2, int* __restrict__ cur3,
                                int* __restrict__ srcs3) {
  int i = blockIdx.x * blockDim.x + threadIdx.x;
  if (i >= 3 * EE) return;
  int which = i >= 2 * EE ? 2 : (i >= EE ? 1 : 0);
  const int* ei = which == 0 ? e0 : (which == 1 ? e1 : e2);
  int e = i - which * EE;
  int d = ei[EE + e];
  int pos = atomicAdd(&cur3[which * NN + d], 1);
  srcs3[pos] = ei[e];
}

// -------- gather+LN: one wave per output row; gene waves do pg+gg ranges; fused LN --------
__global__ __launch_bounds__(256) void gat_gather_ln(
    const int* __restrict__ row3, const int* __restrict__ srcs3,
    const ushort* __restrict__ hb3, const float* __restrict__ als3,
    const float* __restrict__ ald3,
    const float* __restrict__ xg, const float* __restrict__ xp,
    const float* __restrict__ b_gp, const float* __restrict__ b_pg,
    const float* __restrict__ b_gg,
    const float* __restrict__ lng_g, const float* __restrict__ lnb_g,
    const float* __restrict__ lng_p, const float* __restrict__ lnb_p,
    float* __restrict__ out) {
  __shared__ float exs[4][8][68];
  __shared__ int ssrc[4][64];
  const int l = threadIdx.x & 63;
  const int wv = threadIdx.x >> 6;
  const int slot = blockIdx.x * 4 + wv;
  if (slot >= 2 * NN) return;
  const bool gene = (slot < NN);
  const int d = gene ? slot : slot - NN;
  const int sl = l & 31;
  const int half = l >> 5;
  const int hh = sl >> 2;
  float vout[8] = {0.f, 0.f, 0.f, 0.f, 0.f, 0.f, 0.f, 0.f};
  const int nph = gene ? 2 : 1;
  for (int q = 0; q < nph; ++q) {
    const int phase = gene ? (1 + q) : 0;
    const int cslot = phase * NN + d;
    const ushort* hmat = hb3 + (size_t)phase * 12800000;
    const float* al_s = als3 + (size_t)phase * 400000;
    const float* al_d = ald3 + (size_t)phase * 400000;
    const int rs = row3[cslot], re = row3[cslot + 1];
    if (re == rs) continue;
    float4 ad0 = *(const float4*)&al_d[(size_t)d * 8];
    float4 ad1 = *(const float4*)&al_d[(size_t)d * 8 + 4];
    const float ald[8] = {ad0.x, ad0.y, ad0.z, ad0.w, ad1.x, ad1.y, ad1.z, ad1.w};
    float den = 0.f;
    float acc8[8] = {0.f, 0.f, 0.f, 0.f, 0.f, 0.f, 0.f, 0.f};
    const ushort* hrow = hmat + sl * 8;
    for (int base = rs; base < re; base += 64) {
      int e = base + l;
      int chunk = min(64, re - base);
      float ex[8] = {0.f, 0.f, 0.f, 0.f, 0.f, 0.f, 0.f, 0.f};
      int s = 0;
      if (e < re) {
        s = srcs3[e];
        float4 s0 = *(const float4*)&al_s[(size_t)s * 8];
        float4 s1 = *(const float4*)&al_s[(size_t)s * 8 + 4];
        float a[8] = {s0.x + ald[0], s0.y + ald[1], s0.z + ald[2], s0.w + ald[3],
                      s1.x + ald[4], s1.y + ald[5], s1.z + ald[6], s1.w + ald[7]};
#pragma unroll
        for (int h = 0; h < 8; ++h) ex[h] = __expf(fmaxf(a[h], 0.2f * a[h]));
      }
      ssrc[wv][l] = s;
#pragma unroll
      for (int h = 0; h < 8; ++h) exs[wv][h][l] = ex[h];
      // wave-synchronous LDS (per-wave region); 2 edges per half per j-iter
      int chunkr = (chunk + 3) & ~3;
      for (int j = 0; j < chunkr; j += 4) {
        int ja = j + half, jb = j + 2 + half;
        int sa = ssrc[wv][ja], sb = ssrc[wv][jb];
        float wa = exs[wv][hh][ja], wb = exs[wv][hh][jb];
        uint4 pa = *(const uint4*)&hrow[(size_t)sa * 256];
        uint4 pb = *(const uint4*)&hrow[(size_t)sb * 256];
        den += wa + wb;
        acc8[0] += __uint_as_float(pa.x << 16) * wa + __uint_as_float(pb.x << 16) * wb;
        acc8[1] += __uint_as_float(pa.x & 0xffff0000u) * wa + __uint_as_float(pb.x & 0xffff0000u) * wb;
        acc8[2] += __uint_as_float(pa.y << 16) * wa + __uint_as_float(pb.y << 16) * wb;
        acc8[3] += __uint_as_float(pa.y & 0xffff0000u) * wa + __uint_as_float(pb.y & 0xffff0000u) * wb;
        acc8[4] += __uint_as_float(pa.z << 16) * wa + __uint_as_float(pb.z << 16) * wb;
        acc8[5] += __uint_as_float(pa.z & 0xffff0000u) * wa + __uint_as_float(pb.z & 0xffff0000u) * wb;
        acc8[6] += __uint_as_float(pa.w << 16) * wa + __uint_as_float(pb.w << 16) * wb;
        acc8[7] += __uint_as_float(pa.w & 0xffff0000u) * wa + __uint_as_float(pb.w & 0xffff0000u) * wb;
      }
    }
#pragma unroll
    for (int i = 0; i < 8; ++i) acc8[i] += __shfl_xor(acc8[i], 32);
    den += __shfl_xor(den, 32);
    float wd = 1.f / (den + 1e-16f);
#pragma unroll
    for (int i = 0; i < 8; ++i) vout[i] += acc8[i] * wd;
  }
  // residual + biases
  const float* x = gene ? xg : xp;
  float4 xa = *(const float4*)&x[(size_t)d * 256 + sl * 8];
  float4 xbv = *(const float4*)&x[(size_t)d * 256 + sl * 8 + 4];
  float4 ba, bb;
  if (gene) {
    float4 p1 = *(const float4*)&b_pg[sl * 8];
    float4 p2 = *(const float4*)&b_pg[sl * 8 + 4];
    float4 q1 = *(const float4*)&b_gg[sl * 8];
    float4 q2 = *(const float4*)&b_gg[sl * 8 + 4];
    ba = make_float4(p1.x + q1.x, p1.y + q1.y, p1.z + q1.z, p1.w + q1.w);
    bb = make_float4(p2.x + q2.x, p2.y + q2.y, p2.z + q2.z, p2.w + q2.w);
  } else {
    ba = *(const float4*)&b_gp[sl * 8];
    bb = *(const float4*)&b_gp[sl * 8 + 4];
  }
  vout[0] += xa.x + ba.x; vout[1] += xa.y + ba.y; vout[2] += xa.z + ba.z; vout[3] += xa.w + ba.w;
  vout[4] += xbv.x + bb.x; vout[5] += xbv.y + bb.y; vout[6] += xbv.z + bb.z; vout[7] += xbv.w + bb.w;
  // LayerNorm over 256 ch (32 lanes x 8 ch per half; halves hold duplicates)
  float s = 0.f, ss = 0.f;
#pragma unroll
  for (int i = 0; i < 8; ++i) { s += vout[i]; ss += vout[i] * vout[i]; }
#pragma unroll
  for (int off = 1; off < 32; off <<= 1) {
    s += __shfl_xor(s, off);
    ss += __shfl_xor(ss, off);
  }
  float mu = s * (1.f / 256.f);
  float var = ss * (1.f / 256.f) - mu * mu;
  float rstd = rsqrtf(var + 1e-5f);
  const float* lg = gene ? lng_g : lng_p;
  const float* lb = gene ? lnb_g : lnb_p;
  float4 g1 = *(const float4*)&lg[sl * 8];
  float4 g2 = *(const float4*)&lg[sl * 8 + 4];
  float4 c1 = *(const float4*)&lb[sl * 8];
  float4 c2 = *(const float4*)&lb[sl * 8 + 4];
  if (half == 0) {
    float* op = &out[(size_t)slot * 256 + sl * 8];
    float4 o1 = make_float4((vout[0] - mu) * rstd * g1.x + c1.x,
                            (vout[1] - mu) * rstd * g1.y + c1.y,
                            (vout[2] - mu) * rstd * g1.z + c1.z,
                            (vout[3] - mu) * rstd * g1.w + c1.w);
    float4 o2 = make_float4((vout[4] - mu) * rstd * g2.x + c2.x,
                            (vout[5] - mu) * rstd * g2.y + c2.y,
                            (vout[6] - mu) * rstd * g2.z + c2.z,
                            (vout[7] - mu) * rstd * g2.w + c2.w);
    *(float4*)op = o1;
    *(float4*)(op + 4) = o2;
  }
}

extern "C" void kernel_launch(void* const* d_in, const int* in_sizes, int n_in,
                              void* d_out, int out_size, void* d_ws, size_t ws_size,
                              hipStream_t stream) {
  const float* x_gene = (const float*)d_in[0];
  const float* x_pheno = (const float*)d_in[1];
  const int* ei_gp = (const int*)d_in[2];
  const int* ei_pg = (const int*)d_in[3];
  const int* ei_gg = (const int*)d_in[4];
  const float* W_gp = (const float*)d_in[5];
  const float* a_s_gp = (const float*)d_in[6];
  const float* a_d_gp = (const float*)d_in[7];
  const float* b_gp = (const float*)d_in[8];
  const float* W_pg = (const float*)d_in[9];
  const float* a_s_pg = (const float*)d_in[10];
  const float* a_d_pg = (const float*)d_in[11];
  const float* b_pg = (const float*)d_in[12];
  const float* W_gg = (const float*)d_in[13];
  const float* a_s_gg = (const float*)d_in[14];
  const float* a_d_gg = (const float*)d_in[15];
  const float* b_gg = (const float*)d_in[16];
  const float* ln_g_gene = (const float*)d_in[17];
  const float* ln_b_gene = (const float*)d_in[18];
  const float* ln_g_ph = (const float*)d_in[19];
  const float* ln_b_ph = (const float*)d_in[20];
  float* out = (float*)d_out;

  float* ws = (float*)d_ws;
  ushort* hb3 = (ushort*)ws;                    // 3 x 12.8M bf16 = 19.2M f32
  ushort* xb = (ushort*)(ws + 19200000);        // >=100156 rows x 256 bf16
  float* als3 = ws + 32020000;                  // 3 x 400k f32
  float* ald3 = ws + 33220000;                  // 3 x 400k f32
  ushort* WT = (ushort*)(ws + 34420000);        // 3 x 65536 bf16
  ushort* V6T = (ushort*)(ws + 34520000);       // 64 x 256 bf16
  int* ibase = (int*)(ws + 34530000);
  int* cnt3 = ibase;                            // 150016
  int* row3 = ibase + 150016;                   // 150016
  int* cur3 = ibase + 300032;                   // 150016
  int* bsum = ibase + 450048;                   // 256
  int* srcs3 = ibase + 450304;                  // 1500000

  const int NT = 3 * NN;
  const int nb = (NT + 1023) / 1024;  // 147
  const int e3blk = (3 * EE + 255) / 256;

  // ---------- prep: WT, V6T (parallel fold), xb, zero cnt3 ----------
  prep_kernel<<<305 + 2048, 256, 0, stream>>>(W_gp, W_pg, W_gg, a_s_gp, a_s_pg, a_s_gg,
                                              a_d_gp, a_d_pg, a_d_gg, x_gene, x_pheno,
                                              WT, V6T, xb, cnt3);

  // ---------- joint CSR build ----------
  hist3_kernel<<<e3blk, 256, 0, stream>>>(ei_gp, ei_pg, ei_gg, cnt3);
  scan1_kernel<<<nb, 1024, 0, stream>>>(cnt3, bsum, NT);
  scan2_kernel<<<1, 256, 0, stream>>>(bsum, nb);
  scan3_kernel<<<nb, 1024, 0, stream>>>(cnt3, bsum, row3, cur3, NT, 3 * EE);
  permute3_kernel<<<e3blk, 256, 0, stream>>>(ei_gp, ei_pg, ei_gg, cur3, srcs3);

  // ---------- h GEMMs (pure producer) ----------
  gemm_fused<<<dim3(391, 6), 256, 0, stream>>>(xb, WT, hb3);

  // ---------- attention logits (all 6 projections) ----------
  al_mfma<<<(2 * NN + 63) / 64, 256, 0, stream>>>(xb, V6T, als3, ald3);

  // ---------- gather + residual + bias + LayerNorm (writes final output) ----------
  gat_gather_ln<<<(2 * NN + 3) / 4, 256, 0, stream>>>(
      row3, srcs3, hb3, als3, ald3, x_gene, x_pheno, b_gp, b_pg, b_gg,
      ln_g_gene, ln_b_gene, ln_g_ph, ln_b_ph, out);
}

// Round 11
// 401.105 us; speedup vs baseline: 1.7984x; 1.0584x over previous
//
#include <hip/hip_runtime.h>

#define NN 50000
#define EE 500000

typedef unsigned int u32;
typedef unsigned short ushort;
typedef __attribute__((ext_vector_type(8))) short short8v;
typedef __attribute__((ext_vector_type(4))) float float4v;

__device__ __forceinline__ ushort f2b(float f) {  // f32 -> bf16 RNE
  u32 u = __float_as_uint(f);
  u32 r = (u + 0x7fffu + ((u >> 16) & 1u)) >> 16;
  return (ushort)r;
}
__device__ __forceinline__ float bl(u32 q) { return __uint_as_float(q << 16); }
__device__ __forceinline__ float bh(u32 q) { return __uint_as_float(q & 0xffff0000u); }
__device__ __forceinline__ void gload16(const void* g, void* l) {
  __builtin_amdgcn_global_load_lds((const __attribute__((address_space(1))) void*)g,
                                   (__attribute__((address_space(3))) void*)l, 16, 0, 0);
}

// -------- prep: WT transpose | V6T fold | pad | xb convert | edge histogram --------
// requires cnt3 pre-zeroed (memset). b<256: WT. [256,304): V6T. 304: pad.
// [305,2353): xb convert. [2353,...): hist over 3E edges.
__global__ void prep_kernel(const float* __restrict__ W_gp, const float* __restrict__ W_pg,
                            const float* __restrict__ W_gg,
                            const float* __restrict__ as_gp, const float* __restrict__ as_pg,
                            const float* __restrict__ as_gg,
                            const float* __restrict__ ad_gp, const float* __restrict__ ad_pg,
                            const float* __restrict__ ad_gg,
                            const float* __restrict__ xg, const float* __restrict__ xp,
                            const int* __restrict__ e0, const int* __restrict__ e1,
                            const int* __restrict__ e2,
                            ushort* __restrict__ WT, ushort* __restrict__ V6T,
                            ushort* __restrict__ xb, int* __restrict__ cnt3) {
  int b = blockIdx.x;
  int k = threadIdx.x;
  if (b < 256) {  // weight transposes: WT[p][n][k] = W_p[k][n]
    int n = b;
    WT[(size_t)0 * 65536 + n * 256 + k] = f2b(W_gp[k * 256 + n]);
    WT[(size_t)1 * 65536 + n * 256 + k] = f2b(W_pg[k * 256 + n]);
    WT[(size_t)2 * 65536 + n * 256 + k] = f2b(W_gg[k * 256 + n]);
    return;
  }
  if (b < 304) {  // V6T fold: one block per (g,h); v[k] = sum_c W[k][32h+c]*a[h][c]
    int idx = b - 256;
    int g = idx >> 3, h = idx & 7;
    const float* W;
    const float* a;
    switch (g) {
      case 0: W = W_gp; a = as_gp; break;  // als gp (gene rows)
      case 1: W = W_gg; a = as_gg; break;  // als gg (gene rows)
      case 2: W = W_pg; a = ad_pg; break;  // ald pg (gene rows, dst)
      case 3: W = W_gg; a = ad_gg; break;  // ald gg (gene rows, dst)
      case 4: W = W_pg; a = as_pg; break;  // als pg (pheno rows)
      default: W = W_gp; a = ad_gp; break; // ald gp (pheno rows, dst)
    }
    const float4* wrow = (const float4*)&W[(size_t)k * 256 + h * 32];
    const float4* arow = (const float4*)&a[h * 32];
    float s = 0.f;
#pragma unroll
    for (int q = 0; q < 8; ++q) {
      float4 wv = wrow[q];
      float4 av = arow[q];
      s += wv.x * av.x + wv.y * av.y + wv.z * av.z + wv.w * av.w;
    }
    V6T[(size_t)(g * 8 + h) * 256 + k] = f2b(s);
    return;
  }
  if (b == 304) {  // pad cols 48..63
#pragma unroll
    for (int col = 48; col < 64; ++col) V6T[(size_t)col * 256 + k] = 0;
    return;
  }
  if (b < 2353) {  // xb convert (gene rows then pheno rows)
    int i = (b - 305) * 256 + k;
    const int gstride = 2048 * 256;
    const int tot = 2 * NN * 64;
    for (; i < tot; i += gstride) {
      const float* src = (i < NN * 64) ? xg + (size_t)i * 4 : xp + ((size_t)i - (size_t)NN * 64) * 4;
      float4 v = *(const float4*)src;
      ushort4 o;
      o.x = f2b(v.x); o.y = f2b(v.y); o.z = f2b(v.z); o.w = f2b(v.w);
      *(ushort4*)&xb[(size_t)i * 4] = o;
    }
    return;
  }
  // histogram (cnt3 pre-zeroed by memset)
  int i = (b - 2353) * 256 + k;
  if (i >= 3 * EE) return;
  int which = i >= 2 * EE ? 2 : (i >= EE ? 1 : 0);
  const int* ei = which == 0 ? e0 : (which == 1 ? e1 : e2);
  int e = i - which * EE;
  atomicAdd(&cnt3[which * NN + ei[EE + e]], 1);
}

// ---------------- fused compute: y<6 -> h GEMM slices; y==6 -> al projections ----------------
// GEMM: 128x128 tile, BK=32, gload_lds dbuf; swapped-operand MFMA.
// AL: 256 rows/block (4 x 64-row sub-tiles), al6 = x @ V6T.
__global__ __launch_bounds__(256) void fused_compute(
    const ushort* __restrict__ xb, const ushort* __restrict__ WT,
    const ushort* __restrict__ V6T, ushort* __restrict__ hb3,
    float* __restrict__ als3, float* __restrict__ ald3) {
  __shared__ ushort smem[20480];  // 40 KB: gemm As(2x4096)|Bs(2x4096); al BsV(16384)|As2(2x2048)
  const int tid = threadIdx.x;
  const int l = tid & 63, w = tid >> 6;
  const int rr = l & 15, kb = l >> 4;
  if (blockIdx.y < 6) {
    ushort* As = smem;          // [2][4096]
    ushort* Bs = smem + 8192;   // [2][4096]
    const int p = blockIdx.y >> 1;
    const int c0 = (blockIdx.y & 1) * 128;
    const ushort* x = xb + (p == 1 ? (size_t)NN * 256 : 0);
    const ushort* Wp = WT + (size_t)p * 65536 + (size_t)c0 * 256;
    ushort* hb = hb3 + (size_t)p * 12800000;
    const int r0 = blockIdx.x * 128;
    const int wm = w >> 1, wn = w & 1;
    float4v acc[4][4];
#pragma unroll
    for (int mi = 0; mi < 4; ++mi)
#pragma unroll
      for (int ni = 0; ni < 4; ++ni) acc[mi][ni] = (float4v){0.f, 0.f, 0.f, 0.f};
    const int r1 = tid >> 2, g1 = tid & 3;
    const int r2 = 64 + (tid >> 2), g2 = tid & 3;

#define STAGE(buf, k0)                                                               \
  {                                                                                  \
    gload16(&x[(size_t)(r0 + r1) * 256 + (k0) + g1 * 8], &As[(buf) * 4096 + tid * 8]); \
    gload16(&x[(size_t)(r0 + r2) * 256 + (k0) + g2 * 8], &As[(buf) * 4096 + (tid + 256) * 8]); \
    gload16(&Wp[(size_t)r1 * 256 + (k0) + g1 * 8], &Bs[(buf) * 4096 + tid * 8]);     \
    gload16(&Wp[(size_t)r2 * 256 + (k0) + g2 * 8], &Bs[(buf) * 4096 + (tid + 256) * 8]); \
  }

    STAGE(0, 0);
    __syncthreads();
#pragma unroll
    for (int k = 0; k < 8; ++k) {
      const int buf = k & 1;
      if (k < 7) STAGE(buf ^ 1, (k + 1) * 32);
      short8v af[4], bf[4];
#pragma unroll
      for (int t = 0; t < 4; ++t) {
        af[t] = *(const short8v*)&As[buf * 4096 + (wm * 64 + t * 16 + rr) * 32 + kb * 8];
        bf[t] = *(const short8v*)&Bs[buf * 4096 + (wn * 64 + t * 16 + rr) * 32 + kb * 8];
      }
#pragma unroll
      for (int mi = 0; mi < 4; ++mi)
#pragma unroll
        for (int ni = 0; ni < 4; ++ni)
          acc[mi][ni] = __builtin_amdgcn_mfma_f32_16x16x32_bf16(bf[ni], af[mi], acc[mi][ni], 0, 0, 0);
      __syncthreads();
    }
#undef STAGE
#pragma unroll
    for (int mi = 0; mi < 4; ++mi) {
      const int row = r0 + wm * 64 + mi * 16 + rr;
      if (row < NN) {
        ushort* hp = &hb[(size_t)row * 256 + c0 + wn * 64 + kb * 4];
#pragma unroll
        for (int ni = 0; ni < 4; ++ni) {
          uint2 o;
          o.x = (u32)f2b(acc[mi][ni][0]) | ((u32)f2b(acc[mi][ni][1]) << 16);
          o.y = (u32)f2b(acc[mi][ni][2]) | ((u32)f2b(acc[mi][ni][3]) << 16);
          *(uint2*)&hp[ni * 16] = o;
        }
      }
    }
    return;
  }
  // ---- al slice: 256 rows per block ----
  ushort* BsV = smem;           // 64 cols x 256 k
  ushort* As2 = smem + 16384;   // [2][2048]
#pragma unroll
  for (int q = 0; q < 8; ++q) {
    int s = tid + q * 256;
    gload16(&V6T[(size_t)(s >> 5) * 256 + (s & 31) * 8], &BsV[s * 8]);
  }
  for (int t = 0; t < 4; ++t) {
    const int r0 = blockIdx.x * 256 + t * 64;
    gload16(&xb[(size_t)(r0 + (tid >> 2)) * 256 + (tid & 3) * 8], &As2[tid * 8]);
    __syncthreads();
    float4v acc[4];
#pragma unroll
    for (int mi = 0; mi < 4; ++mi) acc[mi] = (float4v){0.f, 0.f, 0.f, 0.f};
#pragma unroll
    for (int k = 0; k < 8; ++k) {
      const int buf = k & 1;
      if (k < 7)
        gload16(&xb[(size_t)(r0 + (tid >> 2)) * 256 + (k + 1) * 32 + (tid & 3) * 8],
                &As2[(buf ^ 1) * 2048 + tid * 8]);
      short8v bfv = *(const short8v*)&BsV[(w * 16 + rr) * 256 + k * 32 + kb * 8];
#pragma unroll
      for (int mi = 0; mi < 4; ++mi) {
        short8v afv = *(const short8v*)&As2[buf * 2048 + (mi * 16 + rr) * 32 + kb * 8];
        acc[mi] = __builtin_amdgcn_mfma_f32_16x16x32_bf16(bfv, afv, acc[mi], 0, 0, 0);
      }
      __syncthreads();
    }
    // lane holds D[row=r0+mi*16+rr][col=w*16+kb*4+i]; group g=w*2+(kb>>1); idx=(kb&1)*4
    const int g = w * 2 + (kb >> 1);
    const int idx = (kb & 1) * 4;
#pragma unroll
    for (int mi = 0; mi < 4; ++mi) {
      int grow = r0 + mi * 16 + rr;
      float4 val = make_float4(acc[mi][0], acc[mi][1], acc[mi][2], acc[mi][3]);
      if (grow < NN) {
        float* arr = g == 0 ? als3 : g == 1 ? als3 + 800000 : g == 2 ? ald3 + 400000
                   : g == 3 ? ald3 + 800000 : nullptr;
        if (arr) *(float4*)&arr[(size_t)grow * 8 + idx] = val;
      } else if (grow < 2 * NN) {
        int r = grow - NN;
        float* arr = g == 4 ? als3 + 400000 : g == 5 ? ald3 : nullptr;
        if (arr) *(float4*)&arr[(size_t)r * 8 + idx] = val;
      }
    }
  }
}

// -------- scan chain --------
__global__ __launch_bounds__(1024) void scan1_kernel(int* __restrict__ cnt,
                                                     int* __restrict__ bsum, int n) {
  __shared__ int ws[16];
  int i = blockIdx.x * 1024 + threadIdx.x;
  const int lane = threadIdx.x & 63, w = threadIdx.x >> 6;
  int v = (i < n) ? cnt[i] : 0;
  int s = v;
#pragma unroll
  for (int off = 1; off < 64; off <<= 1) {
    int t = __shfl_up(s, off);
    if (lane >= off) s += t;
  }
  if (lane == 63) ws[w] = s;
  __syncthreads();
  if (threadIdx.x == 0) {
    int r = 0;
#pragma unroll
    for (int k = 0; k < 16; ++k) { int t = ws[k]; ws[k] = r; r += t; }
    bsum[blockIdx.x] = r;
  }
  __syncthreads();
  if (i < n) cnt[i] = s - v + ws[w];
}

__global__ void scan2_kernel(int* __restrict__ bsum, int nb) {
  __shared__ int ws[4];
  int t = threadIdx.x;  // 256
  const int lane = t & 63, w = t >> 6;
  int v = (t < nb) ? bsum[t] : 0;
  int s = v;
#pragma unroll
  for (int off = 1; off < 64; off <<= 1) {
    int tt = __shfl_up(s, off);
    if (lane >= off) s += tt;
  }
  if (lane == 63) ws[w] = s;
  __syncthreads();
  if (t == 0) {
    int r = 0;
#pragma unroll
    for (int k = 0; k < 4; ++k) { int tt = ws[k]; ws[k] = r; r += tt; }
  }
  __syncthreads();
  if (t < nb) bsum[t] = s - v + ws[w];
}

__global__ __launch_bounds__(1024) void scan3_kernel(const int* __restrict__ part,
                                                     const int* __restrict__ bsum,
                                                     int* __restrict__ row_start,
                                                     int* __restrict__ cursor, int n, int total) {
  int i = blockIdx.x * 1024 + threadIdx.x;
  if (i == 0) row_start[n] = total;
  if (i >= n) return;
  int v = part[i] + bsum[blockIdx.x];
  row_start[i] = v;
  cursor[i] = v;
}

__global__ void permute3_kernel(const int* __restrict__ e0, const int* __restrict__ e1,
                                const int* __restrict__ e2, int* __restrict__ cur3,
                                int* __restrict__ srcs3) {
  int i = blockIdx.x * blockDim.x + threadIdx.x;
  if (i >= 3 * EE) return;
  int which = i >= 2 * EE ? 2 : (i >= EE ? 1 : 0);
  const int* ei = which == 0 ? e0 : (which == 1 ? e1 : e2);
  int e = i - which * EE;
  int d = ei[EE + e];
  int pos = atomicAdd(&cur3[which * NN + d], 1);
  srcs3[pos] = ei[e];
}

// -------- gather+LN: one wave per output row; gene waves do pg+gg; residual from bf16 xb --------
__global__ __launch_bounds__(256) void gat_gather_ln(
    const int* __restrict__ row3, const int* __restrict__ srcs3,
    const ushort* __restrict__ hb3, const float* __restrict__ als3,
    const float* __restrict__ ald3, const ushort* __restrict__ xb,
    const float* __restrict__ b_gp, const float* __restrict__ b_pg,
    const float* __restrict__ b_gg,
    const float* __restrict__ lng_g, const float* __restrict__ lnb_g,
    const float* __restrict__ lng_p, const float* __restrict__ lnb_p,
    float* __restrict__ out) {
  __shared__ float exs[4][8][68];
  __shared__ int ssrc[4][64];
  const int l = threadIdx.x & 63;
  const int wv = threadIdx.x >> 6;
  const int slot = blockIdx.x * 4 + wv;
  if (slot >= 2 * NN) return;
  const bool gene = (slot < NN);
  const int d = gene ? slot : slot - NN;
  const int sl = l & 31;
  const int half = l >> 5;
  const int hh = sl >> 2;
  float vout[8] = {0.f, 0.f, 0.f, 0.f, 0.f, 0.f, 0.f, 0.f};
  const int nph = gene ? 2 : 1;
  for (int q = 0; q < nph; ++q) {
    const int phase = gene ? (1 + q) : 0;
    const int cslot = phase * NN + d;
    const ushort* hmat = hb3 + (size_t)phase * 12800000;
    const float* al_s = als3 + (size_t)phase * 400000;
    const float* al_d = ald3 + (size_t)phase * 400000;
    const int rs = row3[cslot], re = row3[cslot + 1];
    if (re == rs) continue;
    float4 ad0 = *(const float4*)&al_d[(size_t)d * 8];
    float4 ad1 = *(const float4*)&al_d[(size_t)d * 8 + 4];
    const float ald[8] = {ad0.x, ad0.y, ad0.z, ad0.w, ad1.x, ad1.y, ad1.z, ad1.w};
    float den = 0.f;
    float acc8[8] = {0.f, 0.f, 0.f, 0.f, 0.f, 0.f, 0.f, 0.f};
    const ushort* hrow = hmat + sl * 8;
    for (int base = rs; base < re; base += 64) {
      int e = base + l;
      int chunk = min(64, re - base);
      float ex[8] = {0.f, 0.f, 0.f, 0.f, 0.f, 0.f, 0.f, 0.f};
      int s = 0;
      if (e < re) {
        s = srcs3[e];
        float4 s0 = *(const float4*)&al_s[(size_t)s * 8];
        float4 s1 = *(const float4*)&al_s[(size_t)s * 8 + 4];
        float a[8] = {s0.x + ald[0], s0.y + ald[1], s0.z + ald[2], s0.w + ald[3],
                      s1.x + ald[4], s1.y + ald[5], s1.z + ald[6], s1.w + ald[7]};
#pragma unroll
        for (int h = 0; h < 8; ++h) ex[h] = __expf(fmaxf(a[h], 0.2f * a[h]));
      }
      ssrc[wv][l] = s;
#pragma unroll
      for (int h = 0; h < 8; ++h) exs[wv][h][l] = ex[h];
      int chunkr = (chunk + 3) & ~3;
      for (int j = 0; j < chunkr; j += 4) {
        int ja = j + half, jb = j + 2 + half;
        int sa = ssrc[wv][ja], sb = ssrc[wv][jb];
        float wa = exs[wv][hh][ja], wb = exs[wv][hh][jb];
        uint4 pa = *(const uint4*)&hrow[(size_t)sa * 256];
        uint4 pb = *(const uint4*)&hrow[(size_t)sb * 256];
        den += wa + wb;
        acc8[0] += bl(pa.x) * wa + bl(pb.x) * wb;
        acc8[1] += bh(pa.x) * wa + bh(pb.x) * wb;
        acc8[2] += bl(pa.y) * wa + bl(pb.y) * wb;
        acc8[3] += bh(pa.y) * wa + bh(pb.y) * wb;
        acc8[4] += bl(pa.z) * wa + bl(pb.z) * wb;
        acc8[5] += bh(pa.z) * wa + bh(pb.z) * wb;
        acc8[6] += bl(pa.w) * wa + bl(pb.w) * wb;
        acc8[7] += bh(pa.w) * wa + bh(pb.w) * wb;
      }
    }
#pragma unroll
    for (int i = 0; i < 8; ++i) acc8[i] += __shfl_xor(acc8[i], 32);
    den += __shfl_xor(den, 32);
    float wd = 1.f / (den + 1e-16f);
#pragma unroll
    for (int i = 0; i < 8; ++i) vout[i] += acc8[i] * wd;
  }
  // residual (bf16 xb) + biases
  const ushort* xrow = xb + (gene ? 0 : (size_t)NN * 256) + (size_t)d * 256;
  uint4 xq = *(const uint4*)&xrow[sl * 8];
  float4 ba, bb;
  if (gene) {
    float4 p1 = *(const float4*)&b_pg[sl * 8];
    float4 p2 = *(const float4*)&b_pg[sl * 8 + 4];
    float4 q1 = *(const float4*)&b_gg[sl * 8];
    float4 q2 = *(const float4*)&b_gg[sl * 8 + 4];
    ba = make_float4(p1.x + q1.x, p1.y + q1.y, p1.z + q1.z, p1.w + q1.w);
    bb = make_float4(p2.x + q2.x, p2.y + q2.y, p2.z + q2.z, p2.w + q2.w);
  } else {
    ba = *(const float4*)&b_gp[sl * 8];
    bb = *(const float4*)&b_gp[sl * 8 + 4];
  }
  vout[0] += bl(xq.x) + ba.x; vout[1] += bh(xq.x) + ba.y;
  vout[2] += bl(xq.y) + ba.z; vout[3] += bh(xq.y) + ba.w;
  vout[4] += bl(xq.z) + bb.x; vout[5] += bh(xq.z) + bb.y;
  vout[6] += bl(xq.w) + bb.z; vout[7] += bh(xq.w) + bb.w;
  // LayerNorm over 256 ch (32 lanes x 8; halves duplicate)
  float s = 0.f, ss = 0.f;
#pragma unroll
  for (int i = 0; i < 8; ++i) { s += vout[i]; ss += vout[i] * vout[i]; }
#pragma unroll
  for (int off = 1; off < 32; off <<= 1) {
    s += __shfl_xor(s, off);
    ss += __shfl_xor(ss, off);
  }
  float mu = s * (1.f / 256.f);
  float var = ss * (1.f / 256.f) - mu * mu;
  float rstd = rsqrtf(var + 1e-5f);
  const float* lg = gene ? lng_g : lng_p;
  const float* lb = gene ? lnb_g : lnb_p;
  float4 g1 = *(const float4*)&lg[sl * 8];
  float4 g2 = *(const float4*)&lg[sl * 8 + 4];
  float4 c1 = *(const float4*)&lb[sl * 8];
  float4 c2 = *(const float4*)&lb[sl * 8 + 4];
  if (half == 0) {
    float* op = &out[(size_t)slot * 256 + sl * 8];
    float4 o1 = make_float4((vout[0] - mu) * rstd * g1.x + c1.x,
                            (vout[1] - mu) * rstd * g1.y + c1.y,
                            (vout[2] - mu) * rstd * g1.z + c1.z,
                            (vout[3] - mu) * rstd * g1.w + c1.w);
    float4 o2 = make_float4((vout[4] - mu) * rstd * g2.x + c2.x,
                            (vout[5] - mu) * rstd * g2.y + c2.y,
                            (vout[6] - mu) * rstd * g2.z + c2.z,
                            (vout[7] - mu) * rstd * g2.w + c2.w);
    *(float4*)op = o1;
    *(float4*)(op + 4) = o2;
  }
}

extern "C" void kernel_launch(void* const* d_in, const int* in_sizes, int n_in,
                              void* d_out, int out_size, void* d_ws, size_t ws_size,
                              hipStream_t stream) {
  const float* x_gene = (const float*)d_in[0];
  const float* x_pheno = (const float*)d_in[1];
  const int* ei_gp = (const int*)d_in[2];
  const int* ei_pg = (const int*)d_in[3];
  const int* ei_gg = (const int*)d_in[4];
  const float* W_gp = (const float*)d_in[5];
  const float* a_s_gp = (const float*)d_in[6];
  const float* a_d_gp = (const float*)d_in[7];
  const float* b_gp = (const float*)d_in[8];
  const float* W_pg = (const float*)d_in[9];
  const float* a_s_pg = (const float*)d_in[10];
  const float* a_d_pg = (const float*)d_in[11];
  const float* b_pg = (const float*)d_in[12];
  const float* W_gg = (const float*)d_in[13];
  const float* a_s_gg = (const float*)d_in[14];
  const float* a_d_gg = (const float*)d_in[15];
  const float* b_gg = (const float*)d_in[16];
  const float* ln_g_gene = (const float*)d_in[17];
  const float* ln_b_gene = (const float*)d_in[18];
  const float* ln_g_ph = (const float*)d_in[19];
  const float* ln_b_ph = (const float*)d_in[20];
  float* out = (float*)d_out;

  float* ws = (float*)d_ws;
  ushort* hb3 = (ushort*)ws;                    // 3 x 12.8M bf16 = 19.2M f32
  ushort* xb = (ushort*)(ws + 19200000);        // >=100352 rows x 256 bf16
  float* als3 = ws + 32060000;                  // 3 x 400k f32
  float* ald3 = ws + 33260000;                  // 3 x 400k f32
  ushort* WT = (ushort*)(ws + 34460000);        // 3 x 65536 bf16
  ushort* V6T = (ushort*)(ws + 34560000);       // 64 x 256 bf16
  int* ibase = (int*)(ws + 34570000);
  int* cnt3 = ibase;                            // 150016
  int* row3 = ibase + 150016;                   // 150016
  int* cur3 = ibase + 300032;                   // 150016
  int* bsum = ibase + 450048;                   // 256
  int* srcs3 = ibase + 450304;                  // 1500000

  const int NT = 3 * NN;
  const int nb = (NT + 1023) / 1024;  // 147
  const int e3blk = (3 * EE + 255) / 256;  // 5860

  // ---------- cnt3 zero + prep (WT, V6T, xb, hist) ----------
  hipMemsetAsync(cnt3, 0, NT * 4, stream);
  prep_kernel<<<2353 + e3blk, 256, 0, stream>>>(
      W_gp, W_pg, W_gg, a_s_gp, a_s_pg, a_s_gg, a_d_gp, a_d_pg, a_d_gg,
      x_gene, x_pheno, ei_gp, ei_pg, ei_gg, WT, V6T, xb, cnt3);

  // ---------- scan + permute ----------
  scan1_kernel<<<nb, 1024, 0, stream>>>(cnt3, bsum, NT);
  scan2_kernel<<<1, 256, 0, stream>>>(bsum, nb);
  scan3_kernel<<<nb, 1024, 0, stream>>>(cnt3, bsum, row3, cur3, NT, 3 * EE);
  permute3_kernel<<<e3blk, 256, 0, stream>>>(ei_gp, ei_pg, ei_gg, cur3, srcs3);

  // ---------- h GEMMs + al projections (one dispatch) ----------
  fused_compute<<<dim3(391, 7), 256, 0, stream>>>(xb, WT, V6T, hb3, als3, ald3);

  // ---------- gather + residual + bias + LayerNorm ----------
  gat_gather_ln<<<(2 * NN + 3) / 4, 256, 0, stream>>>(
      row3, srcs3, hb3, als3, ald3, xb, b_gp, b_pg, b_gg,
      ln_g_gene, ln_b_gene, ln_g_ph, ln_b_ph, out);
}

// Round 12
// 359.563 us; speedup vs baseline: 2.0062x; 1.1155x over previous
//
#include <hip/hip_runtime.h>

#define NN 50000
#define EE 500000

typedef unsigned int u32;
typedef unsigned short ushort;
typedef __attribute__((ext_vector_type(8))) short short8v;
typedef __attribute__((ext_vector_type(4))) float float4v;

__device__ __forceinline__ ushort f2b(float f) {  // f32 -> bf16 RNE
  u32 u = __float_as_uint(f);
  u32 r = (u + 0x7fffu + ((u >> 16) & 1u)) >> 16;
  return (ushort)r;
}
__device__ __forceinline__ float bl(u32 q) { return __uint_as_float(q << 16); }
__device__ __forceinline__ float bh(u32 q) { return __uint_as_float(q & 0xffff0000u); }
__device__ __forceinline__ void gload16(const void* g, void* l) {
  __builtin_amdgcn_global_load_lds((const __attribute__((address_space(1))) void*)g,
                                   (__attribute__((address_space(3))) void*)l, 16, 0, 0);
}

// -------- prep: WT transpose | V6T fold | pad | xb convert | edge histogram --------
__global__ void prep_kernel(const float* __restrict__ W_gp, const float* __restrict__ W_pg,
                            const float* __restrict__ W_gg,
                            const float* __restrict__ as_gp, const float* __restrict__ as_pg,
                            const float* __restrict__ as_gg,
                            const float* __restrict__ ad_gp, const float* __restrict__ ad_pg,
                            const float* __restrict__ ad_gg,
                            const float* __restrict__ xg, const float* __restrict__ xp,
                            const int* __restrict__ e0, const int* __restrict__ e1,
                            const int* __restrict__ e2,
                            ushort* __restrict__ WT, ushort* __restrict__ V6T,
                            ushort* __restrict__ xb, int* __restrict__ cnt3) {
  int b = blockIdx.x;
  int k = threadIdx.x;
  if (b < 256) {  // weight transposes: WT[p][n][k] = W_p[k][n]
    int n = b;
    WT[(size_t)0 * 65536 + n * 256 + k] = f2b(W_gp[k * 256 + n]);
    WT[(size_t)1 * 65536 + n * 256 + k] = f2b(W_pg[k * 256 + n]);
    WT[(size_t)2 * 65536 + n * 256 + k] = f2b(W_gg[k * 256 + n]);
    return;
  }
  if (b < 304) {  // V6T fold: one block per (g,h); v[k] = sum_c W[k][32h+c]*a[h][c]
    int idx = b - 256;
    int g = idx >> 3, h = idx & 7;
    const float* W;
    const float* a;
    switch (g) {
      case 0: W = W_gp; a = as_gp; break;  // als gp (gene rows)
      case 1: W = W_gg; a = as_gg; break;  // als gg (gene rows)
      case 2: W = W_pg; a = ad_pg; break;  // ald pg (gene rows, dst)
      case 3: W = W_gg; a = ad_gg; break;  // ald gg (gene rows, dst)
      case 4: W = W_pg; a = as_pg; break;  // als pg (pheno rows)
      default: W = W_gp; a = ad_gp; break; // ald gp (pheno rows, dst)
    }
    const float4* wrow = (const float4*)&W[(size_t)k * 256 + h * 32];
    const float4* arow = (const float4*)&a[h * 32];
    float s = 0.f;
#pragma unroll
    for (int q = 0; q < 8; ++q) {
      float4 wv = wrow[q];
      float4 av = arow[q];
      s += wv.x * av.x + wv.y * av.y + wv.z * av.z + wv.w * av.w;
    }
    V6T[(size_t)(g * 8 + h) * 256 + k] = f2b(s);
    return;
  }
  if (b == 304) {  // pad cols 48..63
#pragma unroll
    for (int col = 48; col < 64; ++col) V6T[(size_t)col * 256 + k] = 0;
    return;
  }
  if (b < 2353) {  // xb convert (gene rows then pheno rows)
    int i = (b - 305) * 256 + k;
    const int gstride = 2048 * 256;
    const int tot = 2 * NN * 64;
    for (; i < tot; i += gstride) {
      const float* src = (i < NN * 64) ? xg + (size_t)i * 4 : xp + ((size_t)i - (size_t)NN * 64) * 4;
      float4 v = *(const float4*)src;
      ushort4 o;
      o.x = f2b(v.x); o.y = f2b(v.y); o.z = f2b(v.z); o.w = f2b(v.w);
      *(ushort4*)&xb[(size_t)i * 4] = o;
    }
    return;
  }
  // histogram (cnt3 pre-zeroed by memset)
  int i = (b - 2353) * 256 + k;
  if (i >= 3 * EE) return;
  int which = i >= 2 * EE ? 2 : (i >= EE ? 1 : 0);
  const int* ei = which == 0 ? e0 : (which == 1 ? e1 : e2);
  int e = i - which * EE;
  atomicAdd(&cnt3[which * NN + ei[EE + e]], 1);
}

// ---------------- fused compute: y==0 permute | y in [1,6] h-GEMM | y==7 al ----------------
__global__ __launch_bounds__(256) void fused_compute(
    const ushort* __restrict__ xb, const ushort* __restrict__ WT,
    const ushort* __restrict__ V6T, ushort* __restrict__ hb3,
    float* __restrict__ als3, float* __restrict__ ald3,
    const int* __restrict__ e0, const int* __restrict__ e1, const int* __restrict__ e2,
    int* __restrict__ cur3, int* __restrict__ srcs3) {
  __shared__ ushort smem[20480];  // 40 KB
  const int tid = threadIdx.x;
  const int l = tid & 63, w = tid >> 6;
  const int rr = l & 15, kb = l >> 4;
  if (blockIdx.y == 0) {
    // permute slice: grid-stride over 3E edges (latency work hides under GEMM)
    const int stride = 391 * 256;
    for (int i = blockIdx.x * 256 + tid; i < 3 * EE; i += stride) {
      int which = i >= 2 * EE ? 2 : (i >= EE ? 1 : 0);
      const int* ei = which == 0 ? e0 : (which == 1 ? e1 : e2);
      int e = i - which * EE;
      int d = ei[EE + e];
      int pos = atomicAdd(&cur3[which * NN + d], 1);
      srcs3[pos] = ei[e];
    }
    return;
  }
  if (blockIdx.y < 7) {
    ushort* As = smem;          // [2][4096]
    ushort* Bs = smem + 8192;   // [2][4096]
    const int yy = blockIdx.y - 1;
    const int p = yy >> 1;
    const int c0 = (yy & 1) * 128;
    const ushort* x = xb + (p == 1 ? (size_t)NN * 256 : 0);
    const ushort* Wp = WT + (size_t)p * 65536 + (size_t)c0 * 256;
    ushort* hb = hb3 + (size_t)p * 12800000;
    const int r0 = blockIdx.x * 128;
    const int wm = w >> 1, wn = w & 1;
    float4v acc[4][4];
#pragma unroll
    for (int mi = 0; mi < 4; ++mi)
#pragma unroll
      for (int ni = 0; ni < 4; ++ni) acc[mi][ni] = (float4v){0.f, 0.f, 0.f, 0.f};
    const int r1 = tid >> 2, g1 = tid & 3;
    const int r2 = 64 + (tid >> 2), g2 = tid & 3;

#define STAGE(buf, k0)                                                               \
  {                                                                                  \
    gload16(&x[(size_t)(r0 + r1) * 256 + (k0) + g1 * 8], &As[(buf) * 4096 + tid * 8]); \
    gload16(&x[(size_t)(r0 + r2) * 256 + (k0) + g2 * 8], &As[(buf) * 4096 + (tid + 256) * 8]); \
    gload16(&Wp[(size_t)r1 * 256 + (k0) + g1 * 8], &Bs[(buf) * 4096 + tid * 8]);     \
    gload16(&Wp[(size_t)r2 * 256 + (k0) + g2 * 8], &Bs[(buf) * 4096 + (tid + 256) * 8]); \
  }

    STAGE(0, 0);
    __syncthreads();
#pragma unroll
    for (int k = 0; k < 8; ++k) {
      const int buf = k & 1;
      if (k < 7) STAGE(buf ^ 1, (k + 1) * 32);
      short8v af[4], bf[4];
#pragma unroll
      for (int t = 0; t < 4; ++t) {
        af[t] = *(const short8v*)&As[buf * 4096 + (wm * 64 + t * 16 + rr) * 32 + kb * 8];
        bf[t] = *(const short8v*)&Bs[buf * 4096 + (wn * 64 + t * 16 + rr) * 32 + kb * 8];
      }
#pragma unroll
      for (int mi = 0; mi < 4; ++mi)
#pragma unroll
        for (int ni = 0; ni < 4; ++ni)
          acc[mi][ni] = __builtin_amdgcn_mfma_f32_16x16x32_bf16(bf[ni], af[mi], acc[mi][ni], 0, 0, 0);
      __syncthreads();
    }
#undef STAGE
#pragma unroll
    for (int mi = 0; mi < 4; ++mi) {
      const int row = r0 + wm * 64 + mi * 16 + rr;
      if (row < NN) {
        ushort* hp = &hb[(size_t)row * 256 + c0 + wn * 64 + kb * 4];
#pragma unroll
        for (int ni = 0; ni < 4; ++ni) {
          uint2 o;
          o.x = (u32)f2b(acc[mi][ni][0]) | ((u32)f2b(acc[mi][ni][1]) << 16);
          o.y = (u32)f2b(acc[mi][ni][2]) | ((u32)f2b(acc[mi][ni][3]) << 16);
          *(uint2*)&hp[ni * 16] = o;
        }
      }
    }
    return;
  }
  // ---- al slice: 256 rows per block ----
  ushort* BsV = smem;           // 64 cols x 256 k
  ushort* As2 = smem + 16384;   // [2][2048]
#pragma unroll
  for (int q = 0; q < 8; ++q) {
    int s = tid + q * 256;
    gload16(&V6T[(size_t)(s >> 5) * 256 + (s & 31) * 8], &BsV[s * 8]);
  }
  for (int t = 0; t < 4; ++t) {
    const int r0 = blockIdx.x * 256 + t * 64;
    gload16(&xb[(size_t)(r0 + (tid >> 2)) * 256 + (tid & 3) * 8], &As2[tid * 8]);
    __syncthreads();
    float4v acc[4];
#pragma unroll
    for (int mi = 0; mi < 4; ++mi) acc[mi] = (float4v){0.f, 0.f, 0.f, 0.f};
#pragma unroll
    for (int k = 0; k < 8; ++k) {
      const int buf = k & 1;
      if (k < 7)
        gload16(&xb[(size_t)(r0 + (tid >> 2)) * 256 + (k + 1) * 32 + (tid & 3) * 8],
                &As2[(buf ^ 1) * 2048 + tid * 8]);
      short8v bfv = *(const short8v*)&BsV[(w * 16 + rr) * 256 + k * 32 + kb * 8];
#pragma unroll
      for (int mi = 0; mi < 4; ++mi) {
        short8v afv = *(const short8v*)&As2[buf * 2048 + (mi * 16 + rr) * 32 + kb * 8];
        acc[mi] = __builtin_amdgcn_mfma_f32_16x16x32_bf16(bfv, afv, acc[mi], 0, 0, 0);
      }
      __syncthreads();
    }
    const int g = w * 2 + (kb >> 1);
    const int idx = (kb & 1) * 4;
#pragma unroll
    for (int mi = 0; mi < 4; ++mi) {
      int grow = r0 + mi * 16 + rr;
      float4 val = make_float4(acc[mi][0], acc[mi][1], acc[mi][2], acc[mi][3]);
      if (grow < NN) {
        float* arr = g == 0 ? als3 : g == 1 ? als3 + 800000 : g == 2 ? ald3 + 400000
                   : g == 3 ? ald3 + 800000 : nullptr;
        if (arr) *(float4*)&arr[(size_t)grow * 8 + idx] = val;
      } else if (grow < 2 * NN) {
        int r = grow - NN;
        float* arr = g == 4 ? als3 + 400000 : g == 5 ? ald3 : nullptr;
        if (arr) *(float4*)&arr[(size_t)r * 8 + idx] = val;
      }
    }
  }
}

// -------- scan chain (scan2 folded into scan3 via block-local bsum reduce) --------
__global__ __launch_bounds__(1024) void scan1_kernel(int* __restrict__ cnt,
                                                     int* __restrict__ bsum, int n) {
  __shared__ int ws[16];
  int i = blockIdx.x * 1024 + threadIdx.x;
  const int lane = threadIdx.x & 63, w = threadIdx.x >> 6;
  int v = (i < n) ? cnt[i] : 0;
  int s = v;
#pragma unroll
  for (int off = 1; off < 64; off <<= 1) {
    int t = __shfl_up(s, off);
    if (lane >= off) s += t;
  }
  if (lane == 63) ws[w] = s;
  __syncthreads();
  if (threadIdx.x == 0) {
    int r = 0;
#pragma unroll
    for (int k = 0; k < 16; ++k) { int t = ws[k]; ws[k] = r; r += t; }
    bsum[blockIdx.x] = r;
  }
  __syncthreads();
  if (i < n) cnt[i] = s - v + ws[w];
}

__global__ __launch_bounds__(1024) void scan3_kernel(const int* __restrict__ part,
                                                     const int* __restrict__ bsum,
                                                     int* __restrict__ row_start,
                                                     int* __restrict__ cursor, int n, int total) {
  __shared__ int ws[16];
  __shared__ int boff_s;
  // block-local exclusive offset = sum of bsum[0..blockIdx.x)
  int s = 0;
  for (int t = threadIdx.x; t < blockIdx.x; t += 1024) s += bsum[t];
#pragma unroll
  for (int off = 32; off; off >>= 1) s += __shfl_xor(s, off);
  if ((threadIdx.x & 63) == 0) ws[threadIdx.x >> 6] = s;
  __syncthreads();
  if (threadIdx.x == 0) {
    int r = 0;
#pragma unroll
    for (int k = 0; k < 16; ++k) r += ws[k];
    boff_s = r;
  }
  __syncthreads();
  int i = blockIdx.x * 1024 + threadIdx.x;
  if (i == 0) row_start[n] = total;
  if (i >= n) return;
  int v = part[i] + boff_s;
  row_start[i] = v;
  cursor[i] = v;
}

// -------- gather+LN: one wave per output row; 4-edge MLP unroll; fused LN --------
__global__ __launch_bounds__(256) void gat_gather_ln(
    const int* __restrict__ row3, const int* __restrict__ srcs3,
    const ushort* __restrict__ hb3, const float* __restrict__ als3,
    const float* __restrict__ ald3, const ushort* __restrict__ xb,
    const float* __restrict__ b_gp, const float* __restrict__ b_pg,
    const float* __restrict__ b_gg,
    const float* __restrict__ lng_g, const float* __restrict__ lnb_g,
    const float* __restrict__ lng_p, const float* __restrict__ lnb_p,
    float* __restrict__ out) {
  __shared__ float exs[4][8][68];
  __shared__ int ssrc[4][64];
  const int l = threadIdx.x & 63;
  const int wv = threadIdx.x >> 6;
  const int slot = blockIdx.x * 4 + wv;
  if (slot >= 2 * NN) return;
  const bool gene = (slot < NN);
  const int d = gene ? slot : slot - NN;
  const int sl = l & 31;
  const int half = l >> 5;
  const int hh = sl >> 2;
  float vout[8] = {0.f, 0.f, 0.f, 0.f, 0.f, 0.f, 0.f, 0.f};
  const int nph = gene ? 2 : 1;
  for (int q = 0; q < nph; ++q) {
    const int phase = gene ? (1 + q) : 0;
    const int cslot = phase * NN + d;
    const ushort* hmat = hb3 + (size_t)phase * 12800000;
    const float* al_s = als3 + (size_t)phase * 400000;
    const float* al_d = ald3 + (size_t)phase * 400000;
    const int rs = row3[cslot], re = row3[cslot + 1];
    if (re == rs) continue;
    float4 ad0 = *(const float4*)&al_d[(size_t)d * 8];
    float4 ad1 = *(const float4*)&al_d[(size_t)d * 8 + 4];
    const float ald[8] = {ad0.x, ad0.y, ad0.z, ad0.w, ad1.x, ad1.y, ad1.z, ad1.w};
    float den = 0.f;
    float acc8[8] = {0.f, 0.f, 0.f, 0.f, 0.f, 0.f, 0.f, 0.f};
    const ushort* hrow = hmat + sl * 8;
    for (int base = rs; base < re; base += 64) {
      int e = base + l;
      int chunk = min(64, re - base);
      float ex[8] = {0.f, 0.f, 0.f, 0.f, 0.f, 0.f, 0.f, 0.f};
      int s = 0;
      if (e < re) {
        s = srcs3[e];
        float4 s0 = *(const float4*)&al_s[(size_t)s * 8];
        float4 s1 = *(const float4*)&al_s[(size_t)s * 8 + 4];
        float a[8] = {s0.x + ald[0], s0.y + ald[1], s0.z + ald[2], s0.w + ald[3],
                      s1.x + ald[4], s1.y + ald[5], s1.z + ald[6], s1.w + ald[7]};
#pragma unroll
        for (int h = 0; h < 8; ++h) ex[h] = __expf(fmaxf(a[h], 0.2f * a[h]));
      }
      ssrc[wv][l] = s;
#pragma unroll
      for (int h = 0; h < 8; ++h) exs[wv][h][l] = ex[h];
      // 4 edges per half in flight (8 per wave): deep MLP
      int chunkr = (chunk + 7) & ~7;
      for (int j = 0; j < chunkr; j += 8) {
        int j0 = j + half, j1 = j + 2 + half, j2 = j + 4 + half, j3 = j + 6 + half;
        int s0_ = ssrc[wv][j0], s1_ = ssrc[wv][j1];
        int s2_ = ssrc[wv][j2], s3_ = ssrc[wv][j3];
        float w0 = exs[wv][hh][j0], w1 = exs[wv][hh][j1];
        float w2 = exs[wv][hh][j2], w3 = exs[wv][hh][j3];
        uint4 p0 = *(const uint4*)&hrow[(size_t)s0_ * 256];
        uint4 p1 = *(const uint4*)&hrow[(size_t)s1_ * 256];
        uint4 p2 = *(const uint4*)&hrow[(size_t)s2_ * 256];
        uint4 p3 = *(const uint4*)&hrow[(size_t)s3_ * 256];
        den += (w0 + w1) + (w2 + w3);
        acc8[0] += bl(p0.x) * w0 + bl(p1.x) * w1 + bl(p2.x) * w2 + bl(p3.x) * w3;
        acc8[1] += bh(p0.x) * w0 + bh(p1.x) * w1 + bh(p2.x) * w2 + bh(p3.x) * w3;
        acc8[2] += bl(p0.y) * w0 + bl(p1.y) * w1 + bl(p2.y) * w2 + bl(p3.y) * w3;
        acc8[3] += bh(p0.y) * w0 + bh(p1.y) * w1 + bh(p2.y) * w2 + bh(p3.y) * w3;
        acc8[4] += bl(p0.z) * w0 + bl(p1.z) * w1 + bl(p2.z) * w2 + bl(p3.z) * w3;
        acc8[5] += bh(p0.z) * w0 + bh(p1.z) * w1 + bh(p2.z) * w2 + bh(p3.z) * w3;
        acc8[6] += bl(p0.w) * w0 + bl(p1.w) * w1 + bl(p2.w) * w2 + bl(p3.w) * w3;
        acc8[7] += bh(p0.w) * w0 + bh(p1.w) * w1 + bh(p2.w) * w2 + bh(p3.w) * w3;
      }
    }
#pragma unroll
    for (int i = 0; i < 8; ++i) acc8[i] += __shfl_xor(acc8[i], 32);
    den += __shfl_xor(den, 32);
    float wd = 1.f / (den + 1e-16f);
#pragma unroll
    for (int i = 0; i < 8; ++i) vout[i] += acc8[i] * wd;
  }
  // residual (bf16 xb) + biases
  const ushort* xrow = xb + (gene ? 0 : (size_t)NN * 256) + (size_t)d * 256;
  uint4 xq = *(const uint4*)&xrow[sl * 8];
  float4 ba, bb;
  if (gene) {
    float4 p1 = *(const float4*)&b_pg[sl * 8];
    float4 p2 = *(const float4*)&b_pg[sl * 8 + 4];
    float4 q1 = *(const float4*)&b_gg[sl * 8];
    float4 q2 = *(const float4*)&b_gg[sl * 8 + 4];
    ba = make_float4(p1.x + q1.x, p1.y + q1.y, p1.z + q1.z, p1.w + q1.w);
    bb = make_float4(p2.x + q2.x, p2.y + q2.y, p2.z + q2.z, p2.w + q2.w);
  } else {
    ba = *(const float4*)&b_gp[sl * 8];
    bb = *(const float4*)&b_gp[sl * 8 + 4];
  }
  vout[0] += bl(xq.x) + ba.x; vout[1] += bh(xq.x) + ba.y;
  vout[2] += bl(xq.y) + ba.z; vout[3] += bh(xq.y) + ba.w;
  vout[4] += bl(xq.z) + bb.x; vout[5] += bh(xq.z) + bb.y;
  vout[6] += bl(xq.w) + bb.z; vout[7] += bh(xq.w) + bb.w;
  // LayerNorm over 256 ch (32 lanes x 8; halves duplicate)
  float s = 0.f, ss = 0.f;
#pragma unroll
  for (int i = 0; i < 8; ++i) { s += vout[i]; ss += vout[i] * vout[i]; }
#pragma unroll
  for (int off = 1; off < 32; off <<= 1) {
    s += __shfl_xor(s, off);
    ss += __shfl_xor(ss, off);
  }
  float mu = s * (1.f / 256.f);
  float var = ss * (1.f / 256.f) - mu * mu;
  float rstd = rsqrtf(var + 1e-5f);
  const float* lg = gene ? lng_g : lng_p;
  const float* lb = gene ? lnb_g : lnb_p;
  float4 g1 = *(const float4*)&lg[sl * 8];
  float4 g2 = *(const float4*)&lg[sl * 8 + 4];
  float4 c1 = *(const float4*)&lb[sl * 8];
  float4 c2 = *(const float4*)&lb[sl * 8 + 4];
  if (half == 0) {
    float* op = &out[(size_t)slot * 256 + sl * 8];
    float4 o1 = make_float4((vout[0] - mu) * rstd * g1.x + c1.x,
                            (vout[1] - mu) * rstd * g1.y + c1.y,
                            (vout[2] - mu) * rstd * g1.z + c1.z,
                            (vout[3] - mu) * rstd * g1.w + c1.w);
    float4 o2 = make_float4((vout[4] - mu) * rstd * g2.x + c2.x,
                            (vout[5] - mu) * rstd * g2.y + c2.y,
                            (vout[6] - mu) * rstd * g2.z + c2.z,
                            (vout[7] - mu) * rstd * g2.w + c2.w);
    *(float4*)op = o1;
    *(float4*)(op + 4) = o2;
  }
}

extern "C" void kernel_launch(void* const* d_in, const int* in_sizes, int n_in,
                              void* d_out, int out_size, void* d_ws, size_t ws_size,
                              hipStream_t stream) {
  const float* x_gene = (const float*)d_in[0];
  const float* x_pheno = (const float*)d_in[1];
  const int* ei_gp = (const int*)d_in[2];
  const int* ei_pg = (const int*)d_in[3];
  const int* ei_gg = (const int*)d_in[4];
  const float* W_gp = (const float*)d_in[5];
  const float* a_s_gp = (const float*)d_in[6];
  const float* a_d_gp = (const float*)d_in[7];
  const float* b_gp = (const float*)d_in[8];
  const float* W_pg = (const float*)d_in[9];
  const float* a_s_pg = (const float*)d_in[10];
  const float* a_d_pg = (const float*)d_in[11];
  const float* b_pg = (const float*)d_in[12];
  const float* W_gg = (const float*)d_in[13];
  const float* a_s_gg = (const float*)d_in[14];
  const float* a_d_gg = (const float*)d_in[15];
  const float* b_gg = (const float*)d_in[16];
  const float* ln_g_gene = (const float*)d_in[17];
  const float* ln_b_gene = (const float*)d_in[18];
  const float* ln_g_ph = (const float*)d_in[19];
  const float* ln_b_ph = (const float*)d_in[20];
  float* out = (float*)d_out;

  float* ws = (float*)d_ws;
  ushort* hb3 = (ushort*)ws;                    // 3 x 12.8M bf16 = 19.2M f32
  ushort* xb = (ushort*)(ws + 19200000);        // >=100352 rows x 256 bf16
  float* als3 = ws + 32060000;                  // 3 x 400k f32
  float* ald3 = ws + 33260000;                  // 3 x 400k f32
  ushort* WT = (ushort*)(ws + 34460000);        // 3 x 65536 bf16
  ushort* V6T = (ushort*)(ws + 34560000);       // 64 x 256 bf16
  int* ibase = (int*)(ws + 34570000);
  int* cnt3 = ibase;                            // 150016
  int* row3 = ibase + 150016;                   // 150016
  int* cur3 = ibase + 300032;                   // 150016
  int* bsum = ibase + 450048;                   // 256
  int* srcs3 = ibase + 450304;                  // 1500000

  const int NT = 3 * NN;
  const int nb = (NT + 1023) / 1024;  // 147
  const int e3blk = (3 * EE + 255) / 256;  // 5860

  // ---------- cnt3 zero + prep (WT, V6T, xb, hist) ----------
  hipMemsetAsync(cnt3, 0, NT * 4, stream);
  prep_kernel<<<2353 + e3blk, 256, 0, stream>>>(
      W_gp, W_pg, W_gg, a_s_gp, a_s_pg, a_s_gg, a_d_gp, a_d_pg, a_d_gg,
      x_gene, x_pheno, ei_gp, ei_pg, ei_gg, WT, V6T, xb, cnt3);

  // ---------- scan (scan2 folded into scan3) ----------
  scan1_kernel<<<nb, 1024, 0, stream>>>(cnt3, bsum, NT);
  scan3_kernel<<<nb, 1024, 0, stream>>>(cnt3, bsum, row3, cur3, NT, 3 * EE);

  // ---------- permute + h GEMMs + al projections (one dispatch) ----------
  fused_compute<<<dim3(391, 8), 256, 0, stream>>>(xb, WT, V6T, hb3, als3, ald3,
                                                  ei_gp, ei_pg, ei_gg, cur3, srcs3);

  // ---------- gather + residual + bias + LayerNorm ----------
  gat_gather_ln<<<(2 * NN + 3) / 4, 256, 0, stream>>>(
      row3, srcs3, hb3, als3, ald3, xb, b_gp, b_pg, b_gg,
      ln_g_gene, ln_b_gene, ln_g_ph, ln_b_ph, out);
}